// Round 4
// baseline (1359.168 us; speedup 1.0000x reference)
//
#include <hip/hip_runtime.h>
#include <math.h>

// f32 I/O, f64 accumulation everywhere (bit-exact vs np-f64 ref at f32
// materialization points — absmax 0.0 R4-R10, R12, R13). Workspace 96 MiB.
//
// R14: 3 waves/SIMD for the f64-MFMA conv. R13 measured MfmaUtil 72%,
// Occupancy 22.7% (= 2 waves/SIMD, 188 unified regs/wave, 61 KB LDS).
// Each wave demands the f64 matrix pipe ~67% of wall -> 2 waves can't
// cover each other's barrier/commit/vmcnt phases; 3 waves (3x67%=200%
// demand) should saturate it.
//  - weights staged as f32 again (cvt in compute; VALUBusy 12% has room):
//    LDS 60928 -> 41984 B -> 3 blocks/CU (126 KB < 160 KB).
//  - reg trim: wgoff[9]/lwoff[9] arrays (18 VGPRs) replaced by incremental
//    tap/ci walk in the staging loops (r += 8 per slot: tap = tap?tap-1:8).
//  - __launch_bounds__(256, 3): target <=170 unified regs (64 acc + ~106).
// Numerics identical (same mfma order, same staged values, same epilogue).

constexpr int TOPK_N = 200;

typedef double f64x4 __attribute__((ext_vector_type(4)));

// ---------------------------------------------------------------------------
// L1 only (CIN=3): R10 VALU-f64 tiled fused conv+bias+relu+pool, pipelined.
// Block = 256 threads = 16x16 pooled outputs (32x32 pre-pool), CO_BLK=8.
// ---------------------------------------------------------------------------
template <int CIN, int CI_BLK, int CO_BLK>
__launch_bounds__(256)
__global__ void conv_relu_pool_pipe(const float* __restrict__ in,
                                    const float* __restrict__ wgt,
                                    const float* __restrict__ bias,
                                    float* __restrict__ out,
                                    int Hin, int Win, int Cout) {
    constexpr int SPATIAL = 34 * 34;               // 1156
    constexpr int SSLOT = (SPATIAL + 255) / 256;   // 5
    constexpr int NW = CI_BLK * 9 * CO_BLK;        // weights per chunk
    constexpr int NCHUNK = CIN / CI_BLK;
    const int Hp = Hin >> 1, Wp = Win >> 1;
    const int coChunks = Cout / CO_BLK;
    const int b  = blockIdx.z / coChunks;
    const int cz = blockIdx.z % coChunks;
    const int tid = threadIdx.x;
    const int tx = tid & 15, ty = tid >> 4;
    const int px = (blockIdx.x << 4) + tx;
    const int py = (blockIdx.y << 4) + ty;
    const int iy0 = (blockIdx.y << 5) - 1;
    const int ix0 = (blockIdx.x << 5) - 1;

    __shared__ float  s_in[2][CI_BLK * SPATIAL];
    __shared__ double s_w[2][NW];

    int soff[SSLOT];
#pragma unroll
    for (int s = 0; s < SSLOT; ++s) {
        const int cell = tid + s * 256;
        int g = -1;
        if (cell < SPATIAL) {
            const int ly = cell / 34, lx = cell - ly * 34;
            const int iy = iy0 + ly, ix = ix0 + lx;
            if ((unsigned)iy < (unsigned)Hin && (unsigned)ix < (unsigned)Win)
                g = iy * Win + ix;
        }
        soff[s] = g;
    }
    int wg = -1;
    if (tid < NW) {
        const int co   = tid & (CO_BLK - 1);
        const int rest = tid / CO_BLK;
        const int k    = rest % 9;
        const int ci   = rest / 9;
        wg = ((cz * CO_BLK + co) * CIN + ci) * 9 + k;
    }
    const size_t HW = (size_t)Hin * Win;
    const float* in_b = in + (size_t)b * CIN * HW;

    double acc[CO_BLK][4];
#pragma unroll
    for (int co = 0; co < CO_BLK; ++co)
#pragma unroll
        for (int p = 0; p < 4; ++p) acc[co][p] = 0.0;

    float rin[CI_BLK][SSLOT];
    float rw = 0.f;

#pragma unroll
    for (int ci = 0; ci < CI_BLK; ++ci) {
        const float* src = in_b + ci * HW;
#pragma unroll
        for (int s = 0; s < SSLOT; ++s) {
            const int cell = tid + s * 256;
            float v = 0.f;
            if (cell < SPATIAL) { const int g = soff[s]; if (g >= 0) v = src[g]; }
            rin[ci][s] = v;
        }
    }
    if (tid < NW) rw = wgt[wg];
#pragma unroll
    for (int ci = 0; ci < CI_BLK; ++ci)
#pragma unroll
        for (int s = 0; s < SSLOT; ++s) {
            const int cell = tid + s * 256;
            if (cell < SPATIAL) s_in[0][ci * SPATIAL + cell] = rin[ci][s];
        }
    if (tid < NW) s_w[0][tid] = (double)rw;
    __syncthreads();

    for (int c = 0; c < NCHUNK; ++c) {
        const int buf = c & 1;
        if (c + 1 < NCHUNK) {
            const int c0n = (c + 1) * CI_BLK;
#pragma unroll
            for (int ci = 0; ci < CI_BLK; ++ci) {
                const float* src = in_b + (c0n + ci) * HW;
#pragma unroll
                for (int s = 0; s < SSLOT; ++s) {
                    const int cell = tid + s * 256;
                    float v = 0.f;
                    if (cell < SPATIAL) { const int g = soff[s]; if (g >= 0) v = src[g]; }
                    rin[ci][s] = v;
                }
            }
            if (tid < NW) rw = wgt[wg + c0n * 9];
        }
#pragma unroll 1
        for (int ci = 0; ci < CI_BLK; ++ci) {
            const float* tile = &s_in[buf][ci * SPATIAL];
            double win[4][4];
#pragma unroll
            for (int iy = 0; iy < 4; ++iy) {
                float2 r0 = *(const float2*)&tile[(2 * ty + iy) * 34 + 2 * tx];
                float2 r1 = *(const float2*)&tile[(2 * ty + iy) * 34 + 2 * tx + 2];
                win[iy][0] = (double)r0.x; win[iy][1] = (double)r0.y;
                win[iy][2] = (double)r1.x; win[iy][3] = (double)r1.y;
            }
#pragma unroll
            for (int k = 0; k < 9; ++k) {
                const int ky = k / 3, kx = k % 3;
                const double* wp = &s_w[buf][(ci * 9 + k) * CO_BLK];
                double w[CO_BLK];
#pragma unroll
                for (int co = 0; co < CO_BLK; ++co) w[co] = wp[co];
#pragma unroll
                for (int p = 0; p < 4; ++p) {
                    const double v = win[(p >> 1) + ky][(p & 1) + kx];
#pragma unroll
                    for (int co = 0; co < CO_BLK; ++co)
                        acc[co][p] = fma(v, w[co], acc[co][p]);
                }
            }
        }
        if (c + 1 < NCHUNK) {
#pragma unroll
            for (int ci = 0; ci < CI_BLK; ++ci)
#pragma unroll
                for (int s = 0; s < SSLOT; ++s) {
                    const int cell = tid + s * 256;
                    if (cell < SPATIAL) s_in[buf ^ 1][ci * SPATIAL + cell] = rin[ci][s];
                }
            if (tid < NW) s_w[buf ^ 1][tid] = (double)rw;
            __syncthreads();
        }
    }

#pragma unroll
    for (int co = 0; co < CO_BLK; ++co) {
        const double bd = (double)bias[cz * CO_BLK + co];
        const float e0 = fmaxf((float)(acc[co][0] + bd), 0.f);
        const float e1 = fmaxf((float)(acc[co][1] + bd), 0.f);
        const float e2 = fmaxf((float)(acc[co][2] + bd), 0.f);
        const float e3 = fmaxf((float)(acc[co][3] + bd), 0.f);
        out[((size_t)(b * Cout + cz * CO_BLK + co) * Hp + py) * Wp + px] =
            fmaxf(fmaxf(e0, e1), fmaxf(e2, e3));
    }
}

// ---------------------------------------------------------------------------
// L2-L4: implicit-GEMM conv via v_mfma_f64_16x16x4 (R14).
// Block = 256 thr = 4 waves; tile = 32x8 pre-pool spatial x 32 cout.
// Layouts (CK xdlops, f64 group_size=1):
//   A lane l -> A[i=l&15][k=l>>4];  B lane l -> B[k=l>>4][j=l&15];
//   D lane l reg r -> D[row = 4*r + (l>>4)][col = l&15]   (REGISTER-major)
// Pooling: vertical intra-thread (m pairs), horizontal via __shfl_xor(16).
// LDS: in f32 2x8x360 + w f32 2x8x296 = 41984 B -> 3 blocks/CU.
// Strides 360/296 == 8 mod 32: A/B f32 reads exactly 2-way = free (m136).
// __launch_bounds__(256,3): target 3 waves/SIMD (<=170 unified regs/wave).
// ---------------------------------------------------------------------------
template <int CIN>
__launch_bounds__(256, 3)
__global__ void conv_mfma_f64(const float* __restrict__ in,
                              const float* __restrict__ wgt,
                              const float* __restrict__ bias,
                              float* __restrict__ out,
                              int Hin, int Win, int Cout) {
    constexpr int TW = 34;               // halo tile width  (32 + 2)
    constexpr int CELLS = 34 * 10;       // halo tile cells  (8 + 2 rows)
    constexpr int CH = 360;              // padded per-ci input stride (f32)
    constexpr int CI_CHUNK = 8;
    constexpr int NCHUNK = CIN / CI_CHUNK;
    constexpr int WST = 296;             // per-ci weight stride (f32 elems)

    const int Hp = Hin >> 1, Wp = Win >> 1;
    const int coChunks = Cout >> 5;
    const int b   = blockIdx.z / coChunks;
    const int cob = blockIdx.z % coChunks;
    const int tid = threadIdx.x;
    const int wv  = tid >> 6;
    const int l15 = tid & 15;
    const int l4  = (tid >> 4) & 3;
    const int x0 = blockIdx.x << 5;      // pre-pool tile origin x (32 wide)
    const int y0 = blockIdx.y << 3;      // pre-pool tile origin y (8 tall)

    __shared__ float s_in[2][CI_CHUNK * CH];
    __shared__ float s_w[2][CI_CHUNK * WST];

    // ---- chunk-invariant staging geometry ----
    int soff[2];
#pragma unroll
    for (int s = 0; s < 2; ++s) {
        const int cell = tid + s * 256;
        int g = -1;
        if (cell < CELLS) {
            const int ly = cell / TW, lx = cell - ly * TW;
            const int iy = y0 - 1 + ly, ix = x0 - 1 + lx;
            if ((unsigned)iy < (unsigned)Hin && (unsigned)ix < (unsigned)Win)
                g = iy * Win + ix;
        }
        soff[s] = g;
    }
    // Weight staging walk (replaces wgoff[9]/lwoff[9] arrays, -18 VGPR):
    // slot s handles flat idx = s*256 + tid; co_l = tid&31 (256%32==0),
    // r = s*8 + r0 with r0 = tid>>5; ci = r/9, tap = r%9 walked by
    // r += 8 per slot: tap' = tap ? tap-1 : 8, ci' = ci + (tap!=0).
    const int co_l = tid & 31;
    const int r0   = tid >> 5;           // 0..7
    const int wbase = (cob * 32 + co_l) * CIN * 9;

    const size_t HW = (size_t)Hin * Win;
    const float* in_b = in + (size_t)b * CIN * HW;

    // ---- per-wave mfma read bases (f32 element indices) ----
    int abase[4];
#pragma unroll
    for (int m = 0; m < 4; ++m) {
        const int dy = m >> 1, xh = m & 1;
        abase[m] = l4 * CH + (2 * wv + dy) * TW + xh * 16 + l15;
    }
    const int bbase0 = l4 * WST + l15;
    const int bbase1 = l4 * WST + 16 + l15;

    f64x4 acc[4][2];
#pragma unroll
    for (int m = 0; m < 4; ++m)
#pragma unroll
        for (int n = 0; n < 2; ++n)
#pragma unroll
            for (int j = 0; j < 4; ++j) acc[m][n][j] = 0.0;

    float rin[CI_CHUNK][2];
    float rwt[9];

    // ---- prologue: fetch + commit chunk 0 ----
#pragma unroll
    for (int ci = 0; ci < CI_CHUNK; ++ci) {
        const float* src = in_b + (size_t)ci * HW;
        rin[ci][0] = (soff[0] >= 0) ? src[soff[0]] : 0.f;
        rin[ci][1] = (soff[1] >= 0) ? src[soff[1]] : 0.f;
    }
    {
        int tap = r0, ci = 0;
#pragma unroll
        for (int s = 0; s < 9; ++s) {
            rwt[s] = wgt[wbase + ci * 9 + tap];
            const int nt = tap ? tap - 1 : 8;
            ci += (tap != 0);
            tap = nt;
        }
    }
#pragma unroll
    for (int ci = 0; ci < CI_CHUNK; ++ci) {
        s_in[0][ci * CH + tid] = rin[ci][0];
        if (tid < CELLS - 256) s_in[0][ci * CH + tid + 256] = rin[ci][1];
    }
    {
        int tap = r0, ci = 0;
#pragma unroll
        for (int s = 0; s < 9; ++s) {
            s_w[0][ci * WST + tap * 32 + co_l] = rwt[s];
            const int nt = tap ? tap - 1 : 8;
            ci += (tap != 0);
            tap = nt;
        }
    }
    __syncthreads();

#pragma unroll 2
    for (int c = 0; c < NCHUNK; ++c) {
        const int buf = c & 1;
        // ---- issue next chunk's global loads (land under the mfmas) ----
        if (c + 1 < NCHUNK) {
            const int c0n = (c + 1) * CI_CHUNK;
#pragma unroll
            for (int ci = 0; ci < CI_CHUNK; ++ci) {
                const float* src = in_b + (size_t)(c0n + ci) * HW;
                rin[ci][0] = (soff[0] >= 0) ? src[soff[0]] : 0.f;
                rin[ci][1] = (soff[1] >= 0) ? src[soff[1]] : 0.f;
            }
            int tap = r0, ci = 0;
#pragma unroll
            for (int s = 0; s < 9; ++s) {
                rwt[s] = wgt[wbase + (c0n + ci) * 9 + tap];
                const int nt = tap ? tap - 1 : 8;
                ci += (tap != 0);
                tap = nt;
            }
        }
        // ---- compute: 9 taps x 2 ci4-groups x 8 D-tiles = 144 mfma ----
        {
            const float* ti = &s_in[buf][0];
            const float* tw = &s_w[buf][0];
#pragma unroll
            for (int tap = 0; tap < 9; ++tap) {
                const int ky = tap / 3, kx = tap % 3;
#pragma unroll
                for (int g = 0; g < 2; ++g) {
                    const int ka = g * 4 * CH + ky * TW + kx;
                    const int kb = g * 4 * WST + tap * 32;
                    const double b0 = (double)tw[bbase0 + kb];
                    const double b1 = (double)tw[bbase1 + kb];
                    const double a0 = (double)ti[abase[0] + ka];
                    const double a1 = (double)ti[abase[1] + ka];
                    const double a2 = (double)ti[abase[2] + ka];
                    const double a3 = (double)ti[abase[3] + ka];
                    acc[0][0] = __builtin_amdgcn_mfma_f64_16x16x4f64(a0, b0, acc[0][0], 0, 0, 0);
                    acc[0][1] = __builtin_amdgcn_mfma_f64_16x16x4f64(a0, b1, acc[0][1], 0, 0, 0);
                    acc[1][0] = __builtin_amdgcn_mfma_f64_16x16x4f64(a1, b0, acc[1][0], 0, 0, 0);
                    acc[1][1] = __builtin_amdgcn_mfma_f64_16x16x4f64(a1, b1, acc[1][1], 0, 0, 0);
                    acc[2][0] = __builtin_amdgcn_mfma_f64_16x16x4f64(a2, b0, acc[2][0], 0, 0, 0);
                    acc[2][1] = __builtin_amdgcn_mfma_f64_16x16x4f64(a2, b1, acc[2][1], 0, 0, 0);
                    acc[3][0] = __builtin_amdgcn_mfma_f64_16x16x4f64(a3, b0, acc[3][0], 0, 0, 0);
                    acc[3][1] = __builtin_amdgcn_mfma_f64_16x16x4f64(a3, b1, acc[3][1], 0, 0, 0);
                }
            }
        }
        // ---- commit prefetched regs to the other buffer, one barrier ----
        if (c + 1 < NCHUNK) {
#pragma unroll
            for (int ci = 0; ci < CI_CHUNK; ++ci) {
                s_in[buf ^ 1][ci * CH + tid] = rin[ci][0];
                if (tid < CELLS - 256) s_in[buf ^ 1][ci * CH + tid + 256] = rin[ci][1];
            }
            int tap = r0, ci = 0;
#pragma unroll
            for (int s = 0; s < 9; ++s) {
                s_w[buf ^ 1][ci * WST + tap * 32 + co_l] = rwt[s];
                const int nt = tap ? tap - 1 : 8;
                ci += (tap != 0);
                tap = nt;
            }
            __syncthreads();
        }
    }

    // ---- epilogue: bias (f64) -> relu (f32) -> 2x2 maxpool -> store.
    // Reg r of acc[m][n] holds pre-pool x = x0 + xh*16 + 4r + l4, y = y0+2wv+dy.
    // Vertical pool intra-thread (m pairs); horizontal partner x^1 = lane^16.
    const int yp = (y0 >> 1) + wv;
#pragma unroll
    for (int n = 0; n < 2; ++n) {
        const int co = cob * 32 + n * 16 + l15;
        const double bd = (double)bias[co];
        float* orow = out + (((size_t)b * Cout + co) * Hp + yp) * Wp;
#pragma unroll
        for (int xh = 0; xh < 2; ++xh) {
#pragma unroll
            for (int r = 0; r < 4; ++r) {
                const float e0 = fmaxf((float)(acc[xh][n][r]     + bd), 0.f);
                const float e1 = fmaxf((float)(acc[2 + xh][n][r] + bd), 0.f);
                float v = fmaxf(e0, e1);                 // vertical pool
                const float p = __shfl_xor(v, 16, 64);   // horizontal partner
                v = fmaxf(v, p);
                if ((l4 & 1) == 0) {
                    const int xp = (x0 >> 1) + xh * 8 + 2 * r + (l4 >> 1);
                    orow[xp] = v;
                }
            }
        }
    }
}

// ---------------------------------------------------------------------------
// Head 1x1 conv (256->5, f64) + decode (f64) -> boxes/scores. 32 blocks.
// ---------------------------------------------------------------------------
__launch_bounds__(256)
__global__ void head_decode_k(const float* __restrict__ x4,
                              const float* __restrict__ wh,
                              const float* __restrict__ bh,
                              float* __restrict__ boxes,
                              float* __restrict__ scores) {
    __shared__ float s_wh[5 * 256];
    const int tid = threadIdx.x;
#pragma unroll
    for (int i = 0; i < 5; ++i) s_wh[i * 256 + tid] = wh[i * 256 + tid];
    __syncthreads();

    const int idx  = blockIdx.x * 256 + tid;  // 0..8191
    const int b    = idx >> 10;
    const int cell = idx & 1023;
    const int gy = cell >> 5, gx = cell & 31;

    double a0 = (double)bh[0], a1 = (double)bh[1], a2 = (double)bh[2],
           a3 = (double)bh[3], a4 = (double)bh[4];
    const float* xp = x4 + b * 262144 + cell;
    for (int ci = 0; ci < 256; ++ci) {
        const double v = (double)xp[ci << 10];
        a0 = fma(v, (double)s_wh[0 * 256 + ci], a0);
        a1 = fma(v, (double)s_wh[1 * 256 + ci], a1);
        a2 = fma(v, (double)s_wh[2 * 256 + ci], a2);
        a3 = fma(v, (double)s_wh[3 * 256 + ci], a3);
        a4 = fma(v, (double)s_wh[4 * 256 + ci], a4);
    }
    const double obj = 1.0 / (1.0 + exp(-a0));
    const double txs = 1.0 / (1.0 + exp(-a1));
    const double tys = 1.0 / (1.0 + exp(-a2));
    const double bw  = exp(a3) * 16.0;
    const double bhh = exp(a4) * 16.0;
    const double cx  = gx * 16.0 + txs * 16.0;
    const double cy  = gy * 16.0 + tys * 16.0;
    float* bp = boxes + idx * 4;
    bp[0] = (float)fmin(fmax(cx - bw * 0.5, 0.0), 511.0);
    bp[1] = (float)fmin(fmax(cy - bhh * 0.5, 0.0), 511.0);
    bp[2] = (float)fmin(fmax(cx + bw * 0.5, 0.0), 511.0);
    bp[3] = (float)fmin(fmax(cy + bhh * 0.5, 0.0), 511.0);
    scores[idx] = (float)obj;
}

// ---------------------------------------------------------------------------
// Per-batch top-200 (bitonic, lax.top_k tie semantics) + greedy NMS + output.
// ---------------------------------------------------------------------------
__launch_bounds__(256)
__global__ void topk_nms_k(const float* __restrict__ boxes,
                           const float* __restrict__ scores,
                           float* __restrict__ out5,
                           float* __restrict__ keep_out) {
    const int b = blockIdx.x, tid = threadIdx.x;
    __shared__ unsigned long long key[1024];
    __shared__ float bx1[TOPK_N], by1[TOPK_N], bx2[TOPK_N], by2[TOPK_N];
    __shared__ float sv[TOPK_N], ar[TOPK_N];
    __shared__ int   kp[TOPK_N];

    for (int i = tid; i < 1024; i += 256) {
        float s = scores[b * 1024 + i];
        float m = (s >= 0.01f) ? s : -1.0f;
        unsigned u = __float_as_uint(m);
        u = (u & 0x80000000u) ? ~u : (u | 0x80000000u);
        key[i] = ((unsigned long long)u << 32) | (unsigned)(1023 - i);
    }
    __syncthreads();

    for (int k = 2; k <= 1024; k <<= 1) {
        for (int j = k >> 1; j > 0; j >>= 1) {
            for (int i = tid; i < 1024; i += 256) {
                int l = i ^ j;
                if (l > i) {
                    unsigned long long a = key[i], c = key[l];
                    bool desc = ((i & k) == 0);
                    bool sw = desc ? (a < c) : (a > c);
                    if (sw) { key[i] = c; key[l] = a; }
                }
            }
            __syncthreads();
        }
    }

    for (int i = tid; i < TOPK_N; i += 256) {
        unsigned long long kk = key[i];
        unsigned u = (unsigned)(kk >> 32);
        unsigned bits = (u & 0x80000000u) ? (u & 0x7FFFFFFFu) : ~u;
        float s = __uint_as_float(bits);
        int src = 1023 - (int)(kk & 0xFFFFFFFFu);
        const float4 bb = *(const float4*)(boxes + (b * 1024 + src) * 4);
        bx1[i] = bb.x; by1[i] = bb.y; bx2[i] = bb.z; by2[i] = bb.w;
        sv[i] = s;
        ar[i] = (bb.z - bb.x) * (bb.w - bb.y);
        kp[i] = (s >= 0.01f) ? 1 : 0;
    }
    __syncthreads();

    for (int i = 0; i < TOPK_N; ++i) {
        if (kp[i]) {
            const float X1 = bx1[i], Y1 = by1[i], X2 = bx2[i], Y2 = by2[i], A = ar[i];
            for (int j = tid; j < TOPK_N; j += 256) {
                if (j > i && kp[j]) {
                    float xx1 = fmaxf(X1, bx1[j]);
                    float yy1 = fmaxf(Y1, by1[j]);
                    float xx2 = fminf(X2, bx2[j]);
                    float yy2 = fminf(Y2, by2[j]);
                    float inter = fmaxf(xx2 - xx1, 0.f) * fmaxf(yy2 - yy1, 0.f);
                    float uni = A + ar[j] - inter;
                    float iou = inter / fmaxf(uni, 1e-6f);
                    if (iou > 0.5f) kp[j] = 0;
                }
            }
        }
        __syncthreads();
    }

    for (int i = tid; i < TOPK_N; i += 256) {
        float kf = kp[i] ? 1.f : 0.f;
        float s  = sv[i];
        float sc = (s >= 0.01f) ? s : 0.f;
        float* op = out5 + (b * TOPK_N + i) * 5;
        op[0] = bx1[i] * kf;
        op[1] = by1[i] * kf;
        op[2] = bx2[i] * kf;
        op[3] = by2[i] * kf;
        op[4] = sc * kf;
        keep_out[b * TOPK_N + i] = kf;
    }
}

extern "C" void kernel_launch(void* const* d_in, const int* in_sizes, int n_in,
                              void* d_out, int out_size, void* d_ws, size_t ws_size,
                              hipStream_t stream) {
    const float* images = (const float*)d_in[0];
    const float* w1 = (const float*)d_in[1];
    const float* b1 = (const float*)d_in[2];
    const float* w2 = (const float*)d_in[3];
    const float* b2 = (const float*)d_in[4];
    const float* w3 = (const float*)d_in[5];
    const float* b3 = (const float*)d_in[6];
    const float* w4 = (const float*)d_in[7];
    const float* b4 = (const float*)d_in[8];
    const float* wh = (const float*)d_in[9];
    const float* bh = (const float*)d_in[10];
    float* out = (float*)d_out;

    float* A    = (float*)d_ws;          // x1 [8,32,256,256] -> x3 [8,128,64,64]
    float* Bbuf = A + 16777216;          // x2 [8,64,128,128] -> x4 [8,256,32,32]
    float* boxes  = A + 8388608;         // dead x1 space: 32768 floats
    float* scores = A + 8388608 + 32768; //  8192 floats

    // L1: 3->32, 512x512 -> 256x256. VALU-f64 template (CIN=3 not mfma-shaped).
    conv_relu_pool_pipe<3, 3, 8><<<dim3(16, 16, 8 * 4), 256, 0, stream>>>(
        images, w1, b1, A, 512, 512, 32);
    // L2: 32->64, 256x256 in. MFMA-f64: grid (Wpre/32, Hpre/8, B*Cout/32).
    conv_mfma_f64<32><<<dim3(8, 32, 8 * 2), 256, 0, stream>>>(
        A, w2, b2, Bbuf, 256, 256, 64);
    // L3: 64->128, 128x128 in.
    conv_mfma_f64<64><<<dim3(4, 16, 8 * 4), 256, 0, stream>>>(
        Bbuf, w3, b3, A, 128, 128, 128);
    // L4: 128->256, 64x64 in.
    conv_mfma_f64<128><<<dim3(2, 8, 8 * 8), 256, 0, stream>>>(
        A, w4, b4, Bbuf, 64, 64, 256);
    // Head + decode: 32 blocks, coalesced
    head_decode_k<<<32, 256, 0, stream>>>(Bbuf, wh, bh, boxes, scores);
    // Top-k + NMS + output
    topk_nms_k<<<8, 256, 0, stream>>>(boxes, scores, out, out + 8 * TOPK_N * 5);
}

// Round 5
// 1308.147 us; speedup vs baseline: 1.0390x; 1.0390x over previous
//
#include <hip/hip_runtime.h>
#include <math.h>

// f32 I/O, f64 accumulation everywhere (bit-exact vs np-f64 ref at f32
// materialization points — absmax 0.0 R4-R10, R12, R13). Workspace 96 MiB.
//
// R15: 3 waves/SIMD via a SMALLER ACCUMULATOR, not launch_bounds force.
// R14 post-mortem: (256,3) with acc[4][2]=64 regs spilled (WRITE 32->258MB,
// FETCH +170MB scratch traffic, 409µs/layer). Working set 188 > 170 budget.
// R15 halves the N-tile: 16 couts/block, acc[4] = 32 regs -> ~155 unified
// regs -> 3 waves/SIMD legit. Grid-z doubles (staging 2x, priced: +~20µs
// fetch, VALUBusy ~30%), MFMA demand/wave ~57% x 3 waves = saturation.
// LDS: in f32 2x8x360x4 + w f64 2x8x152x8 = 42496 B -> 3 blocks/CU.
// Tripwire: WRITE_SIZE >> 33MB on conv dispatches = spills -> revert.

constexpr int TOPK_N = 200;

typedef double f64x4 __attribute__((ext_vector_type(4)));

// ---------------------------------------------------------------------------
// L1 only (CIN=3): R10 VALU-f64 tiled fused conv+bias+relu+pool, pipelined.
// Block = 256 threads = 16x16 pooled outputs (32x32 pre-pool), CO_BLK=8.
// ---------------------------------------------------------------------------
template <int CIN, int CI_BLK, int CO_BLK>
__launch_bounds__(256)
__global__ void conv_relu_pool_pipe(const float* __restrict__ in,
                                    const float* __restrict__ wgt,
                                    const float* __restrict__ bias,
                                    float* __restrict__ out,
                                    int Hin, int Win, int Cout) {
    constexpr int SPATIAL = 34 * 34;               // 1156
    constexpr int SSLOT = (SPATIAL + 255) / 256;   // 5
    constexpr int NW = CI_BLK * 9 * CO_BLK;        // weights per chunk
    constexpr int NCHUNK = CIN / CI_BLK;
    const int Hp = Hin >> 1, Wp = Win >> 1;
    const int coChunks = Cout / CO_BLK;
    const int b  = blockIdx.z / coChunks;
    const int cz = blockIdx.z % coChunks;
    const int tid = threadIdx.x;
    const int tx = tid & 15, ty = tid >> 4;
    const int px = (blockIdx.x << 4) + tx;
    const int py = (blockIdx.y << 4) + ty;
    const int iy0 = (blockIdx.y << 5) - 1;
    const int ix0 = (blockIdx.x << 5) - 1;

    __shared__ float  s_in[2][CI_BLK * SPATIAL];
    __shared__ double s_w[2][NW];

    int soff[SSLOT];
#pragma unroll
    for (int s = 0; s < SSLOT; ++s) {
        const int cell = tid + s * 256;
        int g = -1;
        if (cell < SPATIAL) {
            const int ly = cell / 34, lx = cell - ly * 34;
            const int iy = iy0 + ly, ix = ix0 + lx;
            if ((unsigned)iy < (unsigned)Hin && (unsigned)ix < (unsigned)Win)
                g = iy * Win + ix;
        }
        soff[s] = g;
    }
    int wg = -1;
    if (tid < NW) {
        const int co   = tid & (CO_BLK - 1);
        const int rest = tid / CO_BLK;
        const int k    = rest % 9;
        const int ci   = rest / 9;
        wg = ((cz * CO_BLK + co) * CIN + ci) * 9 + k;
    }
    const size_t HW = (size_t)Hin * Win;
    const float* in_b = in + (size_t)b * CIN * HW;

    double acc[CO_BLK][4];
#pragma unroll
    for (int co = 0; co < CO_BLK; ++co)
#pragma unroll
        for (int p = 0; p < 4; ++p) acc[co][p] = 0.0;

    float rin[CI_BLK][SSLOT];
    float rw = 0.f;

#pragma unroll
    for (int ci = 0; ci < CI_BLK; ++ci) {
        const float* src = in_b + ci * HW;
#pragma unroll
        for (int s = 0; s < SSLOT; ++s) {
            const int cell = tid + s * 256;
            float v = 0.f;
            if (cell < SPATIAL) { const int g = soff[s]; if (g >= 0) v = src[g]; }
            rin[ci][s] = v;
        }
    }
    if (tid < NW) rw = wgt[wg];
#pragma unroll
    for (int ci = 0; ci < CI_BLK; ++ci)
#pragma unroll
        for (int s = 0; s < SSLOT; ++s) {
            const int cell = tid + s * 256;
            if (cell < SPATIAL) s_in[0][ci * SPATIAL + cell] = rin[ci][s];
        }
    if (tid < NW) s_w[0][tid] = (double)rw;
    __syncthreads();

    for (int c = 0; c < NCHUNK; ++c) {
        const int buf = c & 1;
        if (c + 1 < NCHUNK) {
            const int c0n = (c + 1) * CI_BLK;
#pragma unroll
            for (int ci = 0; ci < CI_BLK; ++ci) {
                const float* src = in_b + (c0n + ci) * HW;
#pragma unroll
                for (int s = 0; s < SSLOT; ++s) {
                    const int cell = tid + s * 256;
                    float v = 0.f;
                    if (cell < SPATIAL) { const int g = soff[s]; if (g >= 0) v = src[g]; }
                    rin[ci][s] = v;
                }
            }
            if (tid < NW) rw = wgt[wg + c0n * 9];
        }
#pragma unroll 1
        for (int ci = 0; ci < CI_BLK; ++ci) {
            const float* tile = &s_in[buf][ci * SPATIAL];
            double win[4][4];
#pragma unroll
            for (int iy = 0; iy < 4; ++iy) {
                float2 r0 = *(const float2*)&tile[(2 * ty + iy) * 34 + 2 * tx];
                float2 r1 = *(const float2*)&tile[(2 * ty + iy) * 34 + 2 * tx + 2];
                win[iy][0] = (double)r0.x; win[iy][1] = (double)r0.y;
                win[iy][2] = (double)r1.x; win[iy][3] = (double)r1.y;
            }
#pragma unroll
            for (int k = 0; k < 9; ++k) {
                const int ky = k / 3, kx = k % 3;
                const double* wp = &s_w[buf][(ci * 9 + k) * CO_BLK];
                double w[CO_BLK];
#pragma unroll
                for (int co = 0; co < CO_BLK; ++co) w[co] = wp[co];
#pragma unroll
                for (int p = 0; p < 4; ++p) {
                    const double v = win[(p >> 1) + ky][(p & 1) + kx];
#pragma unroll
                    for (int co = 0; co < CO_BLK; ++co)
                        acc[co][p] = fma(v, w[co], acc[co][p]);
                }
            }
        }
        if (c + 1 < NCHUNK) {
#pragma unroll
            for (int ci = 0; ci < CI_BLK; ++ci)
#pragma unroll
                for (int s = 0; s < SSLOT; ++s) {
                    const int cell = tid + s * 256;
                    if (cell < SPATIAL) s_in[buf ^ 1][ci * SPATIAL + cell] = rin[ci][s];
                }
            if (tid < NW) s_w[buf ^ 1][tid] = (double)rw;
            __syncthreads();
        }
    }

#pragma unroll
    for (int co = 0; co < CO_BLK; ++co) {
        const double bd = (double)bias[cz * CO_BLK + co];
        const float e0 = fmaxf((float)(acc[co][0] + bd), 0.f);
        const float e1 = fmaxf((float)(acc[co][1] + bd), 0.f);
        const float e2 = fmaxf((float)(acc[co][2] + bd), 0.f);
        const float e3 = fmaxf((float)(acc[co][3] + bd), 0.f);
        out[((size_t)(b * Cout + cz * CO_BLK + co) * Hp + py) * Wp + px] =
            fmaxf(fmaxf(e0, e1), fmaxf(e2, e3));
    }
}

// ---------------------------------------------------------------------------
// L2-L4: implicit-GEMM conv via v_mfma_f64_16x16x4 (R15).
// Block = 256 thr = 4 waves; tile = 32x8 pre-pool spatial x 16 cout.
// Layouts (CK xdlops, f64 group_size=1):
//   A lane l -> A[i=l&15][k=l>>4];  B lane l -> B[k=l>>4][j=l&15];
//   D lane l reg r -> D[row = 4*r + (l>>4)][col = l&15]   (REGISTER-major)
// acc[4] = 32 regs/lane (m = dy*2+xh). Pooling: vertical intra-thread
// (m pairs), horizontal via __shfl_xor(16), even-l4 lanes store.
// LDS: in f32 2x8x360 + w f64 2x8x152 = 42496 B -> 3 blocks/CU.
// CH=360 == 8 mod 32 -> A b32 reads 2 lanes/bank = free. Weight f64 b64
// reads: even banks only (intrinsic to f64), 2x over b64 minimum — same
// as R13, measured cheap (6.3M conflict-cy ~ 2%).
// ---------------------------------------------------------------------------
template <int CIN>
__launch_bounds__(256, 3)
__global__ void conv_mfma_f64(const float* __restrict__ in,
                              const float* __restrict__ wgt,
                              const float* __restrict__ bias,
                              float* __restrict__ out,
                              int Hin, int Win, int Cout) {
    constexpr int TW = 34;               // halo tile width  (32 + 2)
    constexpr int CELLS = 34 * 10;       // halo tile cells  (8 + 2 rows)
    constexpr int CH = 360;              // padded per-ci input stride (f32)
    constexpr int CI_CHUNK = 8;
    constexpr int NCHUNK = CIN / CI_CHUNK;
    constexpr int WST = 152;             // per-ci weight stride (f64 elems)
    constexpr int NW = CI_CHUNK * 9 * 16;            // 1152 weights/chunk
    constexpr int WSLOT = (NW + 255) / 256;          // 5 (last partial)

    const int Hp = Hin >> 1, Wp = Win >> 1;
    const int coChunks = Cout >> 4;
    const int b   = blockIdx.z / coChunks;
    const int cob = blockIdx.z % coChunks;
    const int tid = threadIdx.x;
    const int wv  = tid >> 6;
    const int l15 = tid & 15;
    const int l4  = (tid >> 4) & 3;
    const int x0 = blockIdx.x << 5;      // pre-pool tile origin x (32 wide)
    const int y0 = blockIdx.y << 3;      // pre-pool tile origin y (8 tall)

    __shared__ float  s_in[2][CI_CHUNK * CH];
    __shared__ double s_w[2][CI_CHUNK * WST];

    // ---- chunk-invariant staging geometry ----
    int soff[2];
#pragma unroll
    for (int s = 0; s < 2; ++s) {
        const int cell = tid + s * 256;
        int g = -1;
        if (cell < CELLS) {
            const int ly = cell / TW, lx = cell - ly * TW;
            const int iy = y0 - 1 + ly, ix = x0 - 1 + lx;
            if ((unsigned)iy < (unsigned)Hin && (unsigned)ix < (unsigned)Win)
                g = iy * Win + ix;
        }
        soff[s] = g;
    }
    // Weight slots: flat idx = s*256 + tid < 1152; co_l = idx&15, r = idx>>4
    // (0..71), tap = r%9, ci = r/9. Chunk c adds c0*9 to the global index.
    int widx[WSLOT], lwidx[WSLOT];
#pragma unroll
    for (int s = 0; s < WSLOT; ++s) {
        const int idx = s * 256 + tid;
        int wgo = -1, lwo = 0;
        if (idx < NW) {
            const int co_l = idx & 15;
            const int r    = idx >> 4;
            const int tap  = r % 9;
            const int ci_l = r / 9;
            wgo = ((cob * 16 + co_l) * CIN + ci_l) * 9 + tap;
            lwo = ci_l * WST + tap * 16 + co_l;
        }
        widx[s] = wgo;
        lwidx[s] = lwo;
    }
    const size_t HW = (size_t)Hin * Win;
    const float* in_b = in + (size_t)b * CIN * HW;

    // ---- per-wave mfma read bases (element indices) ----
    int abase[4];
#pragma unroll
    for (int m = 0; m < 4; ++m) {
        const int dy = m >> 1, xh = m & 1;
        abase[m] = l4 * CH + (2 * wv + dy) * TW + xh * 16 + l15;
    }
    const int bbase = l4 * WST + l15;

    f64x4 acc[4];
#pragma unroll
    for (int m = 0; m < 4; ++m)
#pragma unroll
        for (int j = 0; j < 4; ++j) acc[m][j] = 0.0;

    float rin[CI_CHUNK][2];
    float rwt[WSLOT];

    // ---- prologue: fetch + commit chunk 0 ----
#pragma unroll
    for (int ci = 0; ci < CI_CHUNK; ++ci) {
        const float* src = in_b + (size_t)ci * HW;
        rin[ci][0] = (soff[0] >= 0) ? src[soff[0]] : 0.f;
        rin[ci][1] = (soff[1] >= 0) ? src[soff[1]] : 0.f;
    }
#pragma unroll
    for (int s = 0; s < WSLOT; ++s)
        if (widx[s] >= 0) rwt[s] = wgt[widx[s]];
#pragma unroll
    for (int ci = 0; ci < CI_CHUNK; ++ci) {
        s_in[0][ci * CH + tid] = rin[ci][0];
        if (tid < CELLS - 256) s_in[0][ci * CH + tid + 256] = rin[ci][1];
    }
#pragma unroll
    for (int s = 0; s < WSLOT; ++s)
        if (widx[s] >= 0) s_w[0][lwidx[s]] = (double)rwt[s];
    __syncthreads();

#pragma unroll 2
    for (int c = 0; c < NCHUNK; ++c) {
        const int buf = c & 1;
        // ---- issue next chunk's global loads (land under the mfmas) ----
        if (c + 1 < NCHUNK) {
            const int c0n = (c + 1) * CI_CHUNK;
#pragma unroll
            for (int ci = 0; ci < CI_CHUNK; ++ci) {
                const float* src = in_b + (size_t)(c0n + ci) * HW;
                rin[ci][0] = (soff[0] >= 0) ? src[soff[0]] : 0.f;
                rin[ci][1] = (soff[1] >= 0) ? src[soff[1]] : 0.f;
            }
#pragma unroll
            for (int s = 0; s < WSLOT; ++s)
                if (widx[s] >= 0) rwt[s] = wgt[widx[s] + c0n * 9];
        }
        // ---- compute: 9 taps x 2 ci4-groups x 4 D-tiles = 72 mfma ----
        {
            const float*  ti = &s_in[buf][0];
            const double* tw = &s_w[buf][0];
#pragma unroll
            for (int tap = 0; tap < 9; ++tap) {
                const int ky = tap / 3, kx = tap % 3;
#pragma unroll
                for (int g = 0; g < 2; ++g) {
                    const int ka = g * 4 * CH + ky * TW + kx;
                    const double b0 = tw[bbase + g * 4 * WST + tap * 16];
                    const double a0 = (double)ti[abase[0] + ka];
                    const double a1 = (double)ti[abase[1] + ka];
                    const double a2 = (double)ti[abase[2] + ka];
                    const double a3 = (double)ti[abase[3] + ka];
                    acc[0] = __builtin_amdgcn_mfma_f64_16x16x4f64(a0, b0, acc[0], 0, 0, 0);
                    acc[1] = __builtin_amdgcn_mfma_f64_16x16x4f64(a1, b0, acc[1], 0, 0, 0);
                    acc[2] = __builtin_amdgcn_mfma_f64_16x16x4f64(a2, b0, acc[2], 0, 0, 0);
                    acc[3] = __builtin_amdgcn_mfma_f64_16x16x4f64(a3, b0, acc[3], 0, 0, 0);
                }
            }
        }
        // ---- commit prefetched regs to the other buffer, one barrier ----
        if (c + 1 < NCHUNK) {
#pragma unroll
            for (int ci = 0; ci < CI_CHUNK; ++ci) {
                s_in[buf ^ 1][ci * CH + tid] = rin[ci][0];
                if (tid < CELLS - 256) s_in[buf ^ 1][ci * CH + tid + 256] = rin[ci][1];
            }
#pragma unroll
            for (int s = 0; s < WSLOT; ++s)
                if (widx[s] >= 0) s_w[buf ^ 1][lwidx[s]] = (double)rwt[s];
            __syncthreads();
        }
    }

    // ---- epilogue: bias (f64) -> relu (f32) -> 2x2 maxpool -> store.
    // Reg r of acc[m] holds pre-pool x = x0 + xh*16 + 4r + l4, y = y0+2wv+dy.
    // Vertical pool intra-thread (m pairs); horizontal partner x^1 = lane^16.
    const int yp = (y0 >> 1) + wv;
    {
        const int co = cob * 16 + l15;
        const double bd = (double)bias[co];
        float* orow = out + (((size_t)b * Cout + co) * Hp + yp) * Wp;
#pragma unroll
        for (int xh = 0; xh < 2; ++xh) {
#pragma unroll
            for (int r = 0; r < 4; ++r) {
                const float e0 = fmaxf((float)(acc[xh][r]     + bd), 0.f);
                const float e1 = fmaxf((float)(acc[2 + xh][r] + bd), 0.f);
                float v = fmaxf(e0, e1);                 // vertical pool
                const float p = __shfl_xor(v, 16, 64);   // horizontal partner
                v = fmaxf(v, p);
                if ((l4 & 1) == 0) {
                    const int xp = (x0 >> 1) + xh * 8 + 2 * r + (l4 >> 1);
                    orow[xp] = v;
                }
            }
        }
    }
}

// ---------------------------------------------------------------------------
// Head 1x1 conv (256->5, f64) + decode (f64) -> boxes/scores. 32 blocks.
// ---------------------------------------------------------------------------
__launch_bounds__(256)
__global__ void head_decode_k(const float* __restrict__ x4,
                              const float* __restrict__ wh,
                              const float* __restrict__ bh,
                              float* __restrict__ boxes,
                              float* __restrict__ scores) {
    __shared__ float s_wh[5 * 256];
    const int tid = threadIdx.x;
#pragma unroll
    for (int i = 0; i < 5; ++i) s_wh[i * 256 + tid] = wh[i * 256 + tid];
    __syncthreads();

    const int idx  = blockIdx.x * 256 + tid;  // 0..8191
    const int b    = idx >> 10;
    const int cell = idx & 1023;
    const int gy = cell >> 5, gx = cell & 31;

    double a0 = (double)bh[0], a1 = (double)bh[1], a2 = (double)bh[2],
           a3 = (double)bh[3], a4 = (double)bh[4];
    const float* xp = x4 + b * 262144 + cell;
    for (int ci = 0; ci < 256; ++ci) {
        const double v = (double)xp[ci << 10];
        a0 = fma(v, (double)s_wh[0 * 256 + ci], a0);
        a1 = fma(v, (double)s_wh[1 * 256 + ci], a1);
        a2 = fma(v, (double)s_wh[2 * 256 + ci], a2);
        a3 = fma(v, (double)s_wh[3 * 256 + ci], a3);
        a4 = fma(v, (double)s_wh[4 * 256 + ci], a4);
    }
    const double obj = 1.0 / (1.0 + exp(-a0));
    const double txs = 1.0 / (1.0 + exp(-a1));
    const double tys = 1.0 / (1.0 + exp(-a2));
    const double bw  = exp(a3) * 16.0;
    const double bhh = exp(a4) * 16.0;
    const double cx  = gx * 16.0 + txs * 16.0;
    const double cy  = gy * 16.0 + tys * 16.0;
    float* bp = boxes + idx * 4;
    bp[0] = (float)fmin(fmax(cx - bw * 0.5, 0.0), 511.0);
    bp[1] = (float)fmin(fmax(cy - bhh * 0.5, 0.0), 511.0);
    bp[2] = (float)fmin(fmax(cx + bw * 0.5, 0.0), 511.0);
    bp[3] = (float)fmin(fmax(cy + bhh * 0.5, 0.0), 511.0);
    scores[idx] = (float)obj;
}

// ---------------------------------------------------------------------------
// Per-batch top-200 (bitonic, lax.top_k tie semantics) + greedy NMS + output.
// ---------------------------------------------------------------------------
__launch_bounds__(256)
__global__ void topk_nms_k(const float* __restrict__ boxes,
                           const float* __restrict__ scores,
                           float* __restrict__ out5,
                           float* __restrict__ keep_out) {
    const int b = blockIdx.x, tid = threadIdx.x;
    __shared__ unsigned long long key[1024];
    __shared__ float bx1[TOPK_N], by1[TOPK_N], bx2[TOPK_N], by2[TOPK_N];
    __shared__ float sv[TOPK_N], ar[TOPK_N];
    __shared__ int   kp[TOPK_N];

    for (int i = tid; i < 1024; i += 256) {
        float s = scores[b * 1024 + i];
        float m = (s >= 0.01f) ? s : -1.0f;
        unsigned u = __float_as_uint(m);
        u = (u & 0x80000000u) ? ~u : (u | 0x80000000u);
        key[i] = ((unsigned long long)u << 32) | (unsigned)(1023 - i);
    }
    __syncthreads();

    for (int k = 2; k <= 1024; k <<= 1) {
        for (int j = k >> 1; j > 0; j >>= 1) {
            for (int i = tid; i < 1024; i += 256) {
                int l = i ^ j;
                if (l > i) {
                    unsigned long long a = key[i], c = key[l];
                    bool desc = ((i & k) == 0);
                    bool sw = desc ? (a < c) : (a > c);
                    if (sw) { key[i] = c; key[l] = a; }
                }
            }
            __syncthreads();
        }
    }

    for (int i = tid; i < TOPK_N; i += 256) {
        unsigned long long kk = key[i];
        unsigned u = (unsigned)(kk >> 32);
        unsigned bits = (u & 0x80000000u) ? (u & 0x7FFFFFFFu) : ~u;
        float s = __uint_as_float(bits);
        int src = 1023 - (int)(kk & 0xFFFFFFFFu);
        const float4 bb = *(const float4*)(boxes + (b * 1024 + src) * 4);
        bx1[i] = bb.x; by1[i] = bb.y; bx2[i] = bb.z; by2[i] = bb.w;
        sv[i] = s;
        ar[i] = (bb.z - bb.x) * (bb.w - bb.y);
        kp[i] = (s >= 0.01f) ? 1 : 0;
    }
    __syncthreads();

    for (int i = 0; i < TOPK_N; ++i) {
        if (kp[i]) {
            const float X1 = bx1[i], Y1 = by1[i], X2 = bx2[i], Y2 = by2[i], A = ar[i];
            for (int j = tid; j < TOPK_N; j += 256) {
                if (j > i && kp[j]) {
                    float xx1 = fmaxf(X1, bx1[j]);
                    float yy1 = fmaxf(Y1, by1[j]);
                    float xx2 = fminf(X2, bx2[j]);
                    float yy2 = fminf(Y2, by2[j]);
                    float inter = fmaxf(xx2 - xx1, 0.f) * fmaxf(yy2 - yy1, 0.f);
                    float uni = A + ar[j] - inter;
                    float iou = inter / fmaxf(uni, 1e-6f);
                    if (iou > 0.5f) kp[j] = 0;
                }
            }
        }
        __syncthreads();
    }

    for (int i = tid; i < TOPK_N; i += 256) {
        float kf = kp[i] ? 1.f : 0.f;
        float s  = sv[i];
        float sc = (s >= 0.01f) ? s : 0.f;
        float* op = out5 + (b * TOPK_N + i) * 5;
        op[0] = bx1[i] * kf;
        op[1] = by1[i] * kf;
        op[2] = bx2[i] * kf;
        op[3] = by2[i] * kf;
        op[4] = sc * kf;
        keep_out[b * TOPK_N + i] = kf;
    }
}

extern "C" void kernel_launch(void* const* d_in, const int* in_sizes, int n_in,
                              void* d_out, int out_size, void* d_ws, size_t ws_size,
                              hipStream_t stream) {
    const float* images = (const float*)d_in[0];
    const float* w1 = (const float*)d_in[1];
    const float* b1 = (const float*)d_in[2];
    const float* w2 = (const float*)d_in[3];
    const float* b2 = (const float*)d_in[4];
    const float* w3 = (const float*)d_in[5];
    const float* b3 = (const float*)d_in[6];
    const float* w4 = (const float*)d_in[7];
    const float* b4 = (const float*)d_in[8];
    const float* wh = (const float*)d_in[9];
    const float* bh = (const float*)d_in[10];
    float* out = (float*)d_out;

    float* A    = (float*)d_ws;          // x1 [8,32,256,256] -> x3 [8,128,64,64]
    float* Bbuf = A + 16777216;          // x2 [8,64,128,128] -> x4 [8,256,32,32]
    float* boxes  = A + 8388608;         // dead x1 space: 32768 floats
    float* scores = A + 8388608 + 32768; //  8192 floats

    // L1: 3->32, 512x512 -> 256x256. VALU-f64 template (CIN=3 not mfma-shaped).
    conv_relu_pool_pipe<3, 3, 8><<<dim3(16, 16, 8 * 4), 256, 0, stream>>>(
        images, w1, b1, A, 512, 512, 32);
    // L2: 32->64, 256x256 in. MFMA-f64: grid (Wpre/32, Hpre/8, B*Cout/16).
    conv_mfma_f64<32><<<dim3(8, 32, 8 * 4), 256, 0, stream>>>(
        A, w2, b2, Bbuf, 256, 256, 64);
    // L3: 64->128, 128x128 in.
    conv_mfma_f64<64><<<dim3(4, 16, 8 * 8), 256, 0, stream>>>(
        Bbuf, w3, b3, A, 128, 128, 128);
    // L4: 128->256, 64x64 in.
    conv_mfma_f64<128><<<dim3(2, 8, 8 * 16), 256, 0, stream>>>(
        A, w4, b4, Bbuf, 64, 64, 256);
    // Head + decode: 32 blocks, coalesced
    head_decode_k<<<32, 256, 0, stream>>>(Bbuf, wh, bh, boxes, scores);
    // Top-k + NMS + output
    topk_nms_k<<<8, 256, 0, stream>>>(boxes, scores, out, out + 8 * TOPK_N * 5);
}

// Round 6
// 1246.419 us; speedup vs baseline: 1.0905x; 1.0495x over previous
//
#include <hip/hip_runtime.h>
#include <math.h>

// f32 I/O, f64 accumulation everywhere (bit-exact vs np-f64 ref at f32
// materialization points — absmax 0.0 R4-R13). Workspace 96 MiB.
//
// R16 = R13 (best: 1212 µs, MfmaUtil 72%, 2 waves/SIMD) + async input
// staging via __builtin_amdgcn_global_load_lds.
// R15 post-mortem: halved N-tile FAILED (364->400/layer; staging 2x,
// MfmaUtil down). R13's 28% idle = ~4.4K cy/chunk, equal across layers
// (stall is per-chunk): the register prefetch gets SUNK by the scheduler
// under 188-reg pressure, exposing HBM latency at every vmcnt(0)+barrier.
// global_load_lds has no dest regs -> cannot be sunk; issued at chunk top,
// 9216 cy of MFMA covers the latency. Halo zeros pre-filled once (both
// buffers, chunk-invariant positions); edge lanes skip via exec mask.
// Slot map wave-aligned: slot0 = cells tid, slot1 = cells 212+tid (tid<128),
// overlap 212-255 double-writes identical data (benign).

constexpr int TOPK_N = 200;

typedef double f64x4 __attribute__((ext_vector_type(4)));

// ---------------------------------------------------------------------------
// L1 only (CIN=3): R10 VALU-f64 tiled fused conv+bias+relu+pool, pipelined.
// Block = 256 threads = 16x16 pooled outputs (32x32 pre-pool), CO_BLK=8.
// ---------------------------------------------------------------------------
template <int CIN, int CI_BLK, int CO_BLK>
__launch_bounds__(256)
__global__ void conv_relu_pool_pipe(const float* __restrict__ in,
                                    const float* __restrict__ wgt,
                                    const float* __restrict__ bias,
                                    float* __restrict__ out,
                                    int Hin, int Win, int Cout) {
    constexpr int SPATIAL = 34 * 34;               // 1156
    constexpr int SSLOT = (SPATIAL + 255) / 256;   // 5
    constexpr int NW = CI_BLK * 9 * CO_BLK;        // weights per chunk
    constexpr int NCHUNK = CIN / CI_BLK;
    const int Hp = Hin >> 1, Wp = Win >> 1;
    const int coChunks = Cout / CO_BLK;
    const int b  = blockIdx.z / coChunks;
    const int cz = blockIdx.z % coChunks;
    const int tid = threadIdx.x;
    const int tx = tid & 15, ty = tid >> 4;
    const int px = (blockIdx.x << 4) + tx;
    const int py = (blockIdx.y << 4) + ty;
    const int iy0 = (blockIdx.y << 5) - 1;
    const int ix0 = (blockIdx.x << 5) - 1;

    __shared__ float  s_in[2][CI_BLK * SPATIAL];
    __shared__ double s_w[2][NW];

    int soff[SSLOT];
#pragma unroll
    for (int s = 0; s < SSLOT; ++s) {
        const int cell = tid + s * 256;
        int g = -1;
        if (cell < SPATIAL) {
            const int ly = cell / 34, lx = cell - ly * 34;
            const int iy = iy0 + ly, ix = ix0 + lx;
            if ((unsigned)iy < (unsigned)Hin && (unsigned)ix < (unsigned)Win)
                g = iy * Win + ix;
        }
        soff[s] = g;
    }
    int wg = -1;
    if (tid < NW) {
        const int co   = tid & (CO_BLK - 1);
        const int rest = tid / CO_BLK;
        const int k    = rest % 9;
        const int ci   = rest / 9;
        wg = ((cz * CO_BLK + co) * CIN + ci) * 9 + k;
    }
    const size_t HW = (size_t)Hin * Win;
    const float* in_b = in + (size_t)b * CIN * HW;

    double acc[CO_BLK][4];
#pragma unroll
    for (int co = 0; co < CO_BLK; ++co)
#pragma unroll
        for (int p = 0; p < 4; ++p) acc[co][p] = 0.0;

    float rin[CI_BLK][SSLOT];
    float rw = 0.f;

#pragma unroll
    for (int ci = 0; ci < CI_BLK; ++ci) {
        const float* src = in_b + ci * HW;
#pragma unroll
        for (int s = 0; s < SSLOT; ++s) {
            const int cell = tid + s * 256;
            float v = 0.f;
            if (cell < SPATIAL) { const int g = soff[s]; if (g >= 0) v = src[g]; }
            rin[ci][s] = v;
        }
    }
    if (tid < NW) rw = wgt[wg];
#pragma unroll
    for (int ci = 0; ci < CI_BLK; ++ci)
#pragma unroll
        for (int s = 0; s < SSLOT; ++s) {
            const int cell = tid + s * 256;
            if (cell < SPATIAL) s_in[0][ci * SPATIAL + cell] = rin[ci][s];
        }
    if (tid < NW) s_w[0][tid] = (double)rw;
    __syncthreads();

    for (int c = 0; c < NCHUNK; ++c) {
        const int buf = c & 1;
        if (c + 1 < NCHUNK) {
            const int c0n = (c + 1) * CI_BLK;
#pragma unroll
            for (int ci = 0; ci < CI_BLK; ++ci) {
                const float* src = in_b + (c0n + ci) * HW;
#pragma unroll
                for (int s = 0; s < SSLOT; ++s) {
                    const int cell = tid + s * 256;
                    float v = 0.f;
                    if (cell < SPATIAL) { const int g = soff[s]; if (g >= 0) v = src[g]; }
                    rin[ci][s] = v;
                }
            }
            if (tid < NW) rw = wgt[wg + c0n * 9];
        }
#pragma unroll 1
        for (int ci = 0; ci < CI_BLK; ++ci) {
            const float* tile = &s_in[buf][ci * SPATIAL];
            double win[4][4];
#pragma unroll
            for (int iy = 0; iy < 4; ++iy) {
                float2 r0 = *(const float2*)&tile[(2 * ty + iy) * 34 + 2 * tx];
                float2 r1 = *(const float2*)&tile[(2 * ty + iy) * 34 + 2 * tx + 2];
                win[iy][0] = (double)r0.x; win[iy][1] = (double)r0.y;
                win[iy][2] = (double)r1.x; win[iy][3] = (double)r1.y;
            }
#pragma unroll
            for (int k = 0; k < 9; ++k) {
                const int ky = k / 3, kx = k % 3;
                const double* wp = &s_w[buf][(ci * 9 + k) * CO_BLK];
                double w[CO_BLK];
#pragma unroll
                for (int co = 0; co < CO_BLK; ++co) w[co] = wp[co];
#pragma unroll
                for (int p = 0; p < 4; ++p) {
                    const double v = win[(p >> 1) + ky][(p & 1) + kx];
#pragma unroll
                    for (int co = 0; co < CO_BLK; ++co)
                        acc[co][p] = fma(v, w[co], acc[co][p]);
                }
            }
        }
        if (c + 1 < NCHUNK) {
#pragma unroll
            for (int ci = 0; ci < CI_BLK; ++ci)
#pragma unroll
                for (int s = 0; s < SSLOT; ++s) {
                    const int cell = tid + s * 256;
                    if (cell < SPATIAL) s_in[buf ^ 1][ci * SPATIAL + cell] = rin[ci][s];
                }
            if (tid < NW) s_w[buf ^ 1][tid] = (double)rw;
            __syncthreads();
        }
    }

#pragma unroll
    for (int co = 0; co < CO_BLK; ++co) {
        const double bd = (double)bias[cz * CO_BLK + co];
        const float e0 = fmaxf((float)(acc[co][0] + bd), 0.f);
        const float e1 = fmaxf((float)(acc[co][1] + bd), 0.f);
        const float e2 = fmaxf((float)(acc[co][2] + bd), 0.f);
        const float e3 = fmaxf((float)(acc[co][3] + bd), 0.f);
        out[((size_t)(b * Cout + cz * CO_BLK + co) * Hp + py) * Wp + px] =
            fmaxf(fmaxf(e0, e1), fmaxf(e2, e3));
    }
}

// ---------------------------------------------------------------------------
// L2-L4: implicit-GEMM conv via v_mfma_f64_16x16x4 (R16 = R13 + async stage).
// Block = 256 thr = 4 waves; tile = 32x8 pre-pool spatial x 32 cout.
// Layouts (CK xdlops, f64 group_size=1):
//   A lane l -> A[i=l&15][k=l>>4];  B lane l -> B[k=l>>4][j=l&15];
//   D lane l reg r -> D[row = 4*r + (l>>4)][col = l&15]   (REGISTER-major)
// Pooling: vertical intra-thread (m pairs), horizontal via __shfl_xor(16).
// LDS: in f32 2x8x360 + w f64 2x8x296 = 60928 B (2 blocks/CU).
// Input staging = global_load_lds (cannot be scheduler-sunk; issued at
// chunk top, drained by the existing __syncthreads vmcnt(0)).
// ---------------------------------------------------------------------------
template <int CIN>
__launch_bounds__(256, 2)
__global__ void conv_mfma_f64(const float* __restrict__ in,
                              const float* __restrict__ wgt,
                              const float* __restrict__ bias,
                              float* __restrict__ out,
                              int Hin, int Win, int Cout) {
    constexpr int TW = 34;               // halo tile width  (32 + 2)
    constexpr int CELLS = 34 * 10;       // halo tile cells  (8 + 2 rows) = 340
    constexpr int CH = 360;              // padded per-ci input stride (f32)
    constexpr int CI_CHUNK = 8;
    constexpr int NCHUNK = CIN / CI_CHUNK;
    constexpr int WST = 296;             // per-ci weight stride (f64 elems)

    const int Hp = Hin >> 1, Wp = Win >> 1;
    const int coChunks = Cout >> 5;
    const int b   = blockIdx.z / coChunks;
    const int cob = blockIdx.z % coChunks;
    const int tid = threadIdx.x;
    const int wv  = tid >> 6;
    const int l15 = tid & 15;
    const int l4  = (tid >> 4) & 3;
    const int wb  = tid & 192;           // wave-uniform lane base (tid & ~63)
    const int x0 = blockIdx.x << 5;      // pre-pool tile origin x (32 wide)
    const int y0 = blockIdx.y << 3;      // pre-pool tile origin y (8 tall)

    __shared__ float  s_in[2][CI_CHUNK * CH];
    __shared__ double s_w[2][CI_CHUNK * WST];

    // ---- staging geometry: slot0 = cell tid (all), slot1 = cell 212+tid
    // (tid<128; cells 212..339, overlap 212..255 rewrites identical data).
    int soff[2];
#pragma unroll
    for (int s = 0; s < 2; ++s) {
        const int cell = (s == 0) ? tid : (212 + tid);
        int g = -1;
        if (s == 0 || tid < 128) {
            const int ly = cell / TW, lx = cell - ly * TW;
            const int iy = y0 - 1 + ly, ix = x0 - 1 + lx;
            if ((unsigned)iy < (unsigned)Hin && (unsigned)ix < (unsigned)Win)
                g = iy * Win + ix;
        }
        soff[s] = g;
    }
    int wgoff[9], lwoff[9];              // 2304 = 9*256 weight slots exactly
#pragma unroll
    for (int s = 0; s < 9; ++s) {
        const int idx  = s * 256 + tid;
        const int co_l = idx & 31;
        const int r    = idx >> 5;       // 0..71
        const int tap  = r % 9;
        const int ci_l = r / 9;          // 0..7
        wgoff[s] = ((cob * 32 + co_l) * CIN + ci_l) * 9 + tap;
        lwoff[s] = ci_l * WST + tap * 32 + co_l;
    }
    const size_t HW = (size_t)Hin * Win;
    const float* in_b = in + (size_t)b * CIN * HW;

    // ---- per-wave mfma read bases (element indices) ----
    int abase[4];
#pragma unroll
    for (int m = 0; m < 4; ++m) {
        const int dy = m >> 1, xh = m & 1;
        abase[m] = l4 * CH + (2 * wv + dy) * TW + xh * 16 + l15;
    }
    const int bbase0 = l4 * WST + l15;
    const int bbase1 = l4 * WST + 16 + l15;

    f64x4 acc[4][2];
#pragma unroll
    for (int m = 0; m < 4; ++m)
#pragma unroll
        for (int n = 0; n < 2; ++n)
#pragma unroll
            for (int j = 0; j < 4; ++j) acc[m][n][j] = 0.0;

    float rwt[9];

    // ---- prologue ----
    // Zero the chunk-invariant halo slots in BOTH buffers (edge lanes skip
    // their async copy via exec mask; these zeros persist).
#pragma unroll
    for (int s = 0; s < 2; ++s) {
        const int cell = (s == 0) ? tid : (212 + tid);
        if ((s == 0 || tid < 128) && soff[s] < 0) {
#pragma unroll
            for (int ci = 0; ci < CI_CHUNK; ++ci) {
                s_in[0][ci * CH + cell] = 0.f;
                s_in[1][ci * CH + cell] = 0.f;
            }
        }
    }
    // Stage chunk 0 (async) + weights chunk 0.
#pragma unroll
    for (int ci = 0; ci < CI_CHUNK; ++ci) {
        const float* src = in_b + (size_t)ci * HW;
        if (soff[0] >= 0)
            __builtin_amdgcn_global_load_lds(
                (const __attribute__((address_space(1))) void*)(src + soff[0]),
                (__attribute__((address_space(3))) void*)&s_in[0][ci * CH + wb],
                4, 0, 0);
        if (tid < 128 && soff[1] >= 0)
            __builtin_amdgcn_global_load_lds(
                (const __attribute__((address_space(1))) void*)(src + soff[1]),
                (__attribute__((address_space(3))) void*)&s_in[0][ci * CH + 212 + wb],
                4, 0, 0);
    }
#pragma unroll
    for (int s = 0; s < 9; ++s) rwt[s] = wgt[wgoff[s]];
#pragma unroll
    for (int s = 0; s < 9; ++s) s_w[0][lwoff[s]] = (double)rwt[s];
    __syncthreads();   // drains vmcnt(0): chunk 0 resident

#pragma unroll 2
    for (int c = 0; c < NCHUNK; ++c) {
        const int buf = c & 1;
        // ---- issue next chunk's async copies at chunk TOP (unsinkable) ----
        if (c + 1 < NCHUNK) {
            const int c0n = (c + 1) * CI_CHUNK;
#pragma unroll
            for (int ci = 0; ci < CI_CHUNK; ++ci) {
                const float* src = in_b + (size_t)(c0n + ci) * HW;
                if (soff[0] >= 0)
                    __builtin_amdgcn_global_load_lds(
                        (const __attribute__((address_space(1))) void*)(src + soff[0]),
                        (__attribute__((address_space(3))) void*)&s_in[buf ^ 1][ci * CH + wb],
                        4, 0, 0);
                if (tid < 128 && soff[1] >= 0)
                    __builtin_amdgcn_global_load_lds(
                        (const __attribute__((address_space(1))) void*)(src + soff[1]),
                        (__attribute__((address_space(3))) void*)&s_in[buf ^ 1][ci * CH + 212 + wb],
                        4, 0, 0);
            }
#pragma unroll
            for (int s = 0; s < 9; ++s) rwt[s] = wgt[wgoff[s] + c0n * 9];
        }
        // ---- compute: 9 taps x 2 ci4-groups x 8 D-tiles = 144 mfma ----
        {
            const float*  ti = &s_in[buf][0];
            const double* tw = &s_w[buf][0];
#pragma unroll
            for (int tap = 0; tap < 9; ++tap) {
                const int ky = tap / 3, kx = tap % 3;
#pragma unroll
                for (int g = 0; g < 2; ++g) {
                    const int ka = g * 4 * CH + ky * TW + kx;
                    const int kb = g * 4 * WST + tap * 32;
                    const double b0 = tw[bbase0 + kb];
                    const double b1 = tw[bbase1 + kb];
                    const double a0 = (double)ti[abase[0] + ka];
                    const double a1 = (double)ti[abase[1] + ka];
                    const double a2 = (double)ti[abase[2] + ka];
                    const double a3 = (double)ti[abase[3] + ka];
                    acc[0][0] = __builtin_amdgcn_mfma_f64_16x16x4f64(a0, b0, acc[0][0], 0, 0, 0);
                    acc[0][1] = __builtin_amdgcn_mfma_f64_16x16x4f64(a0, b1, acc[0][1], 0, 0, 0);
                    acc[1][0] = __builtin_amdgcn_mfma_f64_16x16x4f64(a1, b0, acc[1][0], 0, 0, 0);
                    acc[1][1] = __builtin_amdgcn_mfma_f64_16x16x4f64(a1, b1, acc[1][1], 0, 0, 0);
                    acc[2][0] = __builtin_amdgcn_mfma_f64_16x16x4f64(a2, b0, acc[2][0], 0, 0, 0);
                    acc[2][1] = __builtin_amdgcn_mfma_f64_16x16x4f64(a2, b1, acc[2][1], 0, 0, 0);
                    acc[3][0] = __builtin_amdgcn_mfma_f64_16x16x4f64(a3, b0, acc[3][0], 0, 0, 0);
                    acc[3][1] = __builtin_amdgcn_mfma_f64_16x16x4f64(a3, b1, acc[3][1], 0, 0, 0);
                }
            }
        }
        // ---- commit weights to the other buffer, one barrier ----
        if (c + 1 < NCHUNK) {
#pragma unroll
            for (int s = 0; s < 9; ++s) s_w[buf ^ 1][lwoff[s]] = (double)rwt[s];
            __syncthreads();   // vmcnt(0) drain: next chunk's inputs resident
        }
    }

    // ---- epilogue: bias (f64) -> relu (f32) -> 2x2 maxpool -> store.
    // Reg r of acc[m][n] holds pre-pool x = x0 + xh*16 + 4r + l4, y = y0+2wv+dy.
    // Vertical pool intra-thread (m pairs); horizontal partner x^1 = lane^16.
    const int yp = (y0 >> 1) + wv;
#pragma unroll
    for (int n = 0; n < 2; ++n) {
        const int co = cob * 32 + n * 16 + l15;
        const double bd = (double)bias[co];
        float* orow = out + (((size_t)b * Cout + co) * Hp + yp) * Wp;
#pragma unroll
        for (int xh = 0; xh < 2; ++xh) {
#pragma unroll
            for (int r = 0; r < 4; ++r) {
                const float e0 = fmaxf((float)(acc[xh][n][r]     + bd), 0.f);
                const float e1 = fmaxf((float)(acc[2 + xh][n][r] + bd), 0.f);
                float v = fmaxf(e0, e1);                 // vertical pool
                const float p = __shfl_xor(v, 16, 64);   // horizontal partner
                v = fmaxf(v, p);
                if ((l4 & 1) == 0) {
                    const int xp = (x0 >> 1) + xh * 8 + 2 * r + (l4 >> 1);
                    orow[xp] = v;
                }
            }
        }
    }
}

// ---------------------------------------------------------------------------
// Head 1x1 conv (256->5, f64) + decode (f64) -> boxes/scores. 32 blocks.
// ---------------------------------------------------------------------------
__launch_bounds__(256)
__global__ void head_decode_k(const float* __restrict__ x4,
                              const float* __restrict__ wh,
                              const float* __restrict__ bh,
                              float* __restrict__ boxes,
                              float* __restrict__ scores) {
    __shared__ float s_wh[5 * 256];
    const int tid = threadIdx.x;
#pragma unroll
    for (int i = 0; i < 5; ++i) s_wh[i * 256 + tid] = wh[i * 256 + tid];
    __syncthreads();

    const int idx  = blockIdx.x * 256 + tid;  // 0..8191
    const int b    = idx >> 10;
    const int cell = idx & 1023;
    const int gy = cell >> 5, gx = cell & 31;

    double a0 = (double)bh[0], a1 = (double)bh[1], a2 = (double)bh[2],
           a3 = (double)bh[3], a4 = (double)bh[4];
    const float* xp = x4 + b * 262144 + cell;
    for (int ci = 0; ci < 256; ++ci) {
        const double v = (double)xp[ci << 10];
        a0 = fma(v, (double)s_wh[0 * 256 + ci], a0);
        a1 = fma(v, (double)s_wh[1 * 256 + ci], a1);
        a2 = fma(v, (double)s_wh[2 * 256 + ci], a2);
        a3 = fma(v, (double)s_wh[3 * 256 + ci], a3);
        a4 = fma(v, (double)s_wh[4 * 256 + ci], a4);
    }
    const double obj = 1.0 / (1.0 + exp(-a0));
    const double txs = 1.0 / (1.0 + exp(-a1));
    const double tys = 1.0 / (1.0 + exp(-a2));
    const double bw  = exp(a3) * 16.0;
    const double bhh = exp(a4) * 16.0;
    const double cx  = gx * 16.0 + txs * 16.0;
    const double cy  = gy * 16.0 + tys * 16.0;
    float* bp = boxes + idx * 4;
    bp[0] = (float)fmin(fmax(cx - bw * 0.5, 0.0), 511.0);
    bp[1] = (float)fmin(fmax(cy - bhh * 0.5, 0.0), 511.0);
    bp[2] = (float)fmin(fmax(cx + bw * 0.5, 0.0), 511.0);
    bp[3] = (float)fmin(fmax(cy + bhh * 0.5, 0.0), 511.0);
    scores[idx] = (float)obj;
}

// ---------------------------------------------------------------------------
// Per-batch top-200 (bitonic, lax.top_k tie semantics) + greedy NMS + output.
// ---------------------------------------------------------------------------
__launch_bounds__(256)
__global__ void topk_nms_k(const float* __restrict__ boxes,
                           const float* __restrict__ scores,
                           float* __restrict__ out5,
                           float* __restrict__ keep_out) {
    const int b = blockIdx.x, tid = threadIdx.x;
    __shared__ unsigned long long key[1024];
    __shared__ float bx1[TOPK_N], by1[TOPK_N], bx2[TOPK_N], by2[TOPK_N];
    __shared__ float sv[TOPK_N], ar[TOPK_N];
    __shared__ int   kp[TOPK_N];

    for (int i = tid; i < 1024; i += 256) {
        float s = scores[b * 1024 + i];
        float m = (s >= 0.01f) ? s : -1.0f;
        unsigned u = __float_as_uint(m);
        u = (u & 0x80000000u) ? ~u : (u | 0x80000000u);
        key[i] = ((unsigned long long)u << 32) | (unsigned)(1023 - i);
    }
    __syncthreads();

    for (int k = 2; k <= 1024; k <<= 1) {
        for (int j = k >> 1; j > 0; j >>= 1) {
            for (int i = tid; i < 1024; i += 256) {
                int l = i ^ j;
                if (l > i) {
                    unsigned long long a = key[i], c = key[l];
                    bool desc = ((i & k) == 0);
                    bool sw = desc ? (a < c) : (a > c);
                    if (sw) { key[i] = c; key[l] = a; }
                }
            }
            __syncthreads();
        }
    }

    for (int i = tid; i < TOPK_N; i += 256) {
        unsigned long long kk = key[i];
        unsigned u = (unsigned)(kk >> 32);
        unsigned bits = (u & 0x80000000u) ? (u & 0x7FFFFFFFu) : ~u;
        float s = __uint_as_float(bits);
        int src = 1023 - (int)(kk & 0xFFFFFFFFu);
        const float4 bb = *(const float4*)(boxes + (b * 1024 + src) * 4);
        bx1[i] = bb.x; by1[i] = bb.y; bx2[i] = bb.z; by2[i] = bb.w;
        sv[i] = s;
        ar[i] = (bb.z - bb.x) * (bb.w - bb.y);
        kp[i] = (s >= 0.01f) ? 1 : 0;
    }
    __syncthreads();

    for (int i = 0; i < TOPK_N; ++i) {
        if (kp[i]) {
            const float X1 = bx1[i], Y1 = by1[i], X2 = bx2[i], Y2 = by2[i], A = ar[i];
            for (int j = tid; j < TOPK_N; j += 256) {
                if (j > i && kp[j]) {
                    float xx1 = fmaxf(X1, bx1[j]);
                    float yy1 = fmaxf(Y1, by1[j]);
                    float xx2 = fminf(X2, bx2[j]);
                    float yy2 = fminf(Y2, by2[j]);
                    float inter = fmaxf(xx2 - xx1, 0.f) * fmaxf(yy2 - yy1, 0.f);
                    float uni = A + ar[j] - inter;
                    float iou = inter / fmaxf(uni, 1e-6f);
                    if (iou > 0.5f) kp[j] = 0;
                }
            }
        }
        __syncthreads();
    }

    for (int i = tid; i < TOPK_N; i += 256) {
        float kf = kp[i] ? 1.f : 0.f;
        float s  = sv[i];
        float sc = (s >= 0.01f) ? s : 0.f;
        float* op = out5 + (b * TOPK_N + i) * 5;
        op[0] = bx1[i] * kf;
        op[1] = by1[i] * kf;
        op[2] = bx2[i] * kf;
        op[3] = by2[i] * kf;
        op[4] = sc * kf;
        keep_out[b * TOPK_N + i] = kf;
    }
}

extern "C" void kernel_launch(void* const* d_in, const int* in_sizes, int n_in,
                              void* d_out, int out_size, void* d_ws, size_t ws_size,
                              hipStream_t stream) {
    const float* images = (const float*)d_in[0];
    const float* w1 = (const float*)d_in[1];
    const float* b1 = (const float*)d_in[2];
    const float* w2 = (const float*)d_in[3];
    const float* b2 = (const float*)d_in[4];
    const float* w3 = (const float*)d_in[5];
    const float* b3 = (const float*)d_in[6];
    const float* w4 = (const float*)d_in[7];
    const float* b4 = (const float*)d_in[8];
    const float* wh = (const float*)d_in[9];
    const float* bh = (const float*)d_in[10];
    float* out = (float*)d_out;

    float* A    = (float*)d_ws;          // x1 [8,32,256,256] -> x3 [8,128,64,64]
    float* Bbuf = A + 16777216;          // x2 [8,64,128,128] -> x4 [8,256,32,32]
    float* boxes  = A + 8388608;         // dead x1 space: 32768 floats
    float* scores = A + 8388608 + 32768; //  8192 floats

    // L1: 3->32, 512x512 -> 256x256. VALU-f64 template (CIN=3 not mfma-shaped).
    conv_relu_pool_pipe<3, 3, 8><<<dim3(16, 16, 8 * 4), 256, 0, stream>>>(
        images, w1, b1, A, 512, 512, 32);
    // L2: 32->64, 256x256 in. MFMA-f64: grid (Wpre/32, Hpre/8, B*Cout/32).
    conv_mfma_f64<32><<<dim3(8, 32, 8 * 2), 256, 0, stream>>>(
        A, w2, b2, Bbuf, 256, 256, 64);
    // L3: 64->128, 128x128 in.
    conv_mfma_f64<64><<<dim3(4, 16, 8 * 4), 256, 0, stream>>>(
        Bbuf, w3, b3, A, 128, 128, 128);
    // L4: 128->256, 64x64 in.
    conv_mfma_f64<128><<<dim3(2, 8, 8 * 8), 256, 0, stream>>>(
        A, w4, b4, Bbuf, 64, 64, 256);
    // Head + decode: 32 blocks, coalesced
    head_decode_k<<<32, 256, 0, stream>>>(Bbuf, wh, bh, boxes, scores);
    // Top-k + NMS + output
    topk_nms_k<<<8, 256, 0, stream>>>(boxes, scores, out, out + 8 * TOPK_N * 5);
}

// Round 7
// 1233.981 us; speedup vs baseline: 1.1014x; 1.0101x over previous
//
#include <hip/hip_runtime.h>
#include <math.h>

// f32 I/O, f64 accumulation everywhere (bit-exact vs np-f64 ref at f32
// materialization points — absmax 0.0 R4-R16). Workspace 96 MiB.
//
// R17 = R13 (best: 1212 µs, MfmaUtil 72%, 2 waves/SIMD) + co-resident-block
// DESYNC. R16 falsified the load-latency theory (unsinkable async staging
// changed nothing), so the ~9K cy/chunk-period idle is the barrier convoy:
// the 2 blocks sharing each CU are dispatched together, run identical code,
// and stay phase-locked -> both drain at their barriers simultaneously and
// the f64 MFMA pipe goes idle. Fix: blocks in odd occupancy rounds
// ((linear>>8)&1 at 2 blocks/CU on 256 CUs) sleep ~12.8K cy (half a chunk
// period) at entry; identical durations preserve the anti-phase for the
// whole dispatch. Timing-only: numerics identical (absmax 0.0).

constexpr int TOPK_N = 200;

typedef double f64x4 __attribute__((ext_vector_type(4)));

// ---------------------------------------------------------------------------
// L1 only (CIN=3): R10 VALU-f64 tiled fused conv+bias+relu+pool, pipelined.
// Block = 256 threads = 16x16 pooled outputs (32x32 pre-pool), CO_BLK=8.
// ---------------------------------------------------------------------------
template <int CIN, int CI_BLK, int CO_BLK>
__launch_bounds__(256)
__global__ void conv_relu_pool_pipe(const float* __restrict__ in,
                                    const float* __restrict__ wgt,
                                    const float* __restrict__ bias,
                                    float* __restrict__ out,
                                    int Hin, int Win, int Cout) {
    constexpr int SPATIAL = 34 * 34;               // 1156
    constexpr int SSLOT = (SPATIAL + 255) / 256;   // 5
    constexpr int NW = CI_BLK * 9 * CO_BLK;        // weights per chunk
    constexpr int NCHUNK = CIN / CI_BLK;
    const int Hp = Hin >> 1, Wp = Win >> 1;
    const int coChunks = Cout / CO_BLK;
    const int b  = blockIdx.z / coChunks;
    const int cz = blockIdx.z % coChunks;
    const int tid = threadIdx.x;
    const int tx = tid & 15, ty = tid >> 4;
    const int px = (blockIdx.x << 4) + tx;
    const int py = (blockIdx.y << 4) + ty;
    const int iy0 = (blockIdx.y << 5) - 1;
    const int ix0 = (blockIdx.x << 5) - 1;

    __shared__ float  s_in[2][CI_BLK * SPATIAL];
    __shared__ double s_w[2][NW];

    int soff[SSLOT];
#pragma unroll
    for (int s = 0; s < SSLOT; ++s) {
        const int cell = tid + s * 256;
        int g = -1;
        if (cell < SPATIAL) {
            const int ly = cell / 34, lx = cell - ly * 34;
            const int iy = iy0 + ly, ix = ix0 + lx;
            if ((unsigned)iy < (unsigned)Hin && (unsigned)ix < (unsigned)Win)
                g = iy * Win + ix;
        }
        soff[s] = g;
    }
    int wg = -1;
    if (tid < NW) {
        const int co   = tid & (CO_BLK - 1);
        const int rest = tid / CO_BLK;
        const int k    = rest % 9;
        const int ci   = rest / 9;
        wg = ((cz * CO_BLK + co) * CIN + ci) * 9 + k;
    }
    const size_t HW = (size_t)Hin * Win;
    const float* in_b = in + (size_t)b * CIN * HW;

    double acc[CO_BLK][4];
#pragma unroll
    for (int co = 0; co < CO_BLK; ++co)
#pragma unroll
        for (int p = 0; p < 4; ++p) acc[co][p] = 0.0;

    float rin[CI_BLK][SSLOT];
    float rw = 0.f;

#pragma unroll
    for (int ci = 0; ci < CI_BLK; ++ci) {
        const float* src = in_b + ci * HW;
#pragma unroll
        for (int s = 0; s < SSLOT; ++s) {
            const int cell = tid + s * 256;
            float v = 0.f;
            if (cell < SPATIAL) { const int g = soff[s]; if (g >= 0) v = src[g]; }
            rin[ci][s] = v;
        }
    }
    if (tid < NW) rw = wgt[wg];
#pragma unroll
    for (int ci = 0; ci < CI_BLK; ++ci)
#pragma unroll
        for (int s = 0; s < SSLOT; ++s) {
            const int cell = tid + s * 256;
            if (cell < SPATIAL) s_in[0][ci * SPATIAL + cell] = rin[ci][s];
        }
    if (tid < NW) s_w[0][tid] = (double)rw;
    __syncthreads();

    for (int c = 0; c < NCHUNK; ++c) {
        const int buf = c & 1;
        if (c + 1 < NCHUNK) {
            const int c0n = (c + 1) * CI_BLK;
#pragma unroll
            for (int ci = 0; ci < CI_BLK; ++ci) {
                const float* src = in_b + (c0n + ci) * HW;
#pragma unroll
                for (int s = 0; s < SSLOT; ++s) {
                    const int cell = tid + s * 256;
                    float v = 0.f;
                    if (cell < SPATIAL) { const int g = soff[s]; if (g >= 0) v = src[g]; }
                    rin[ci][s] = v;
                }
            }
            if (tid < NW) rw = wgt[wg + c0n * 9];
        }
#pragma unroll 1
        for (int ci = 0; ci < CI_BLK; ++ci) {
            const float* tile = &s_in[buf][ci * SPATIAL];
            double win[4][4];
#pragma unroll
            for (int iy = 0; iy < 4; ++iy) {
                float2 r0 = *(const float2*)&tile[(2 * ty + iy) * 34 + 2 * tx];
                float2 r1 = *(const float2*)&tile[(2 * ty + iy) * 34 + 2 * tx + 2];
                win[iy][0] = (double)r0.x; win[iy][1] = (double)r0.y;
                win[iy][2] = (double)r1.x; win[iy][3] = (double)r1.y;
            }
#pragma unroll
            for (int k = 0; k < 9; ++k) {
                const int ky = k / 3, kx = k % 3;
                const double* wp = &s_w[buf][(ci * 9 + k) * CO_BLK];
                double w[CO_BLK];
#pragma unroll
                for (int co = 0; co < CO_BLK; ++co) w[co] = wp[co];
#pragma unroll
                for (int p = 0; p < 4; ++p) {
                    const double v = win[(p >> 1) + ky][(p & 1) + kx];
#pragma unroll
                    for (int co = 0; co < CO_BLK; ++co)
                        acc[co][p] = fma(v, w[co], acc[co][p]);
                }
            }
        }
        if (c + 1 < NCHUNK) {
#pragma unroll
            for (int ci = 0; ci < CI_BLK; ++ci)
#pragma unroll
                for (int s = 0; s < SSLOT; ++s) {
                    const int cell = tid + s * 256;
                    if (cell < SPATIAL) s_in[buf ^ 1][ci * SPATIAL + cell] = rin[ci][s];
                }
            if (tid < NW) s_w[buf ^ 1][tid] = (double)rw;
            __syncthreads();
        }
    }

#pragma unroll
    for (int co = 0; co < CO_BLK; ++co) {
        const double bd = (double)bias[cz * CO_BLK + co];
        const float e0 = fmaxf((float)(acc[co][0] + bd), 0.f);
        const float e1 = fmaxf((float)(acc[co][1] + bd), 0.f);
        const float e2 = fmaxf((float)(acc[co][2] + bd), 0.f);
        const float e3 = fmaxf((float)(acc[co][3] + bd), 0.f);
        out[((size_t)(b * Cout + cz * CO_BLK + co) * Hp + py) * Wp + px] =
            fmaxf(fmaxf(e0, e1), fmaxf(e2, e3));
    }
}

// ---------------------------------------------------------------------------
// L2-L4: implicit-GEMM conv via v_mfma_f64_16x16x4 (R17 = R13 + desync).
// Block = 256 thr = 4 waves; tile = 32x8 pre-pool spatial x 32 cout.
// Layouts (CK xdlops, f64 group_size=1):
//   A lane l -> A[i=l&15][k=l>>4];  B lane l -> B[k=l>>4][j=l&15];
//   D lane l reg r -> D[row = 4*r + (l>>4)][col = l&15]   (REGISTER-major)
// Pooling: vertical intra-thread (m pairs), horizontal via __shfl_xor(16).
// LDS: in f32 2x8x360 + w f64 2x8x296 = 60928 B (2 blocks/CU).
// Anti-phase: odd occupancy rounds sleep ~12.8K cy at entry so the two
// co-resident blocks' barrier drains land under each other's compute.
// ---------------------------------------------------------------------------
template <int CIN>
__launch_bounds__(256, 2)
__global__ void conv_mfma_f64(const float* __restrict__ in,
                              const float* __restrict__ wgt,
                              const float* __restrict__ bias,
                              float* __restrict__ out,
                              int Hin, int Win, int Cout) {
    constexpr int TW = 34;               // halo tile width  (32 + 2)
    constexpr int CELLS = 34 * 10;       // halo tile cells  (8 + 2 rows)
    constexpr int CH = 360;              // padded per-ci input stride (f32)
    constexpr int CI_CHUNK = 8;
    constexpr int NCHUNK = CIN / CI_CHUNK;
    constexpr int WST = 296;             // per-ci weight stride (f64 elems)

    // ---- co-resident desync: odd rounds (2 blocks/CU, 256 CUs) start
    // ~half a chunk-period late; identical durations keep the anti-phase.
    {
        const int lin = blockIdx.x +
                        (int)gridDim.x * (blockIdx.y + (int)gridDim.y * blockIdx.z);
        if ((lin >> 8) & 1) {
            __builtin_amdgcn_s_sleep(100);
            __builtin_amdgcn_s_sleep(100);
        }
    }

    const int Hp = Hin >> 1, Wp = Win >> 1;
    const int coChunks = Cout >> 5;
    const int b   = blockIdx.z / coChunks;
    const int cob = blockIdx.z % coChunks;
    const int tid = threadIdx.x;
    const int wv  = tid >> 6;
    const int l15 = tid & 15;
    const int l4  = (tid >> 4) & 3;
    const int x0 = blockIdx.x << 5;      // pre-pool tile origin x (32 wide)
    const int y0 = blockIdx.y << 3;      // pre-pool tile origin y (8 tall)

    __shared__ float  s_in[2][CI_CHUNK * CH];
    __shared__ double s_w[2][CI_CHUNK * WST];

    // ---- chunk-invariant staging geometry ----
    int soff[2];
#pragma unroll
    for (int s = 0; s < 2; ++s) {
        const int cell = tid + s * 256;
        int g = -1;
        if (cell < CELLS) {
            const int ly = cell / TW, lx = cell - ly * TW;
            const int iy = y0 - 1 + ly, ix = x0 - 1 + lx;
            if ((unsigned)iy < (unsigned)Hin && (unsigned)ix < (unsigned)Win)
                g = iy * Win + ix;
        }
        soff[s] = g;
    }
    int wgoff[9], lwoff[9];              // 2304 = 9*256 weight slots exactly
#pragma unroll
    for (int s = 0; s < 9; ++s) {
        const int idx  = s * 256 + tid;
        const int co_l = idx & 31;
        const int r    = idx >> 5;       // 0..71
        const int tap  = r % 9;
        const int ci_l = r / 9;          // 0..7
        wgoff[s] = ((cob * 32 + co_l) * CIN + ci_l) * 9 + tap;
        lwoff[s] = ci_l * WST + tap * 32 + co_l;
    }
    const size_t HW = (size_t)Hin * Win;
    const float* in_b = in + (size_t)b * CIN * HW;

    // ---- per-wave mfma read bases (element indices) ----
    int abase[4];
#pragma unroll
    for (int m = 0; m < 4; ++m) {
        const int dy = m >> 1, xh = m & 1;
        abase[m] = l4 * CH + (2 * wv + dy) * TW + xh * 16 + l15;
    }
    const int bbase0 = l4 * WST + l15;
    const int bbase1 = l4 * WST + 16 + l15;

    f64x4 acc[4][2];
#pragma unroll
    for (int m = 0; m < 4; ++m)
#pragma unroll
        for (int n = 0; n < 2; ++n)
#pragma unroll
            for (int j = 0; j < 4; ++j) acc[m][n][j] = 0.0;

    float rin[CI_CHUNK][2];
    float rwt[9];

    // ---- prologue: fetch + commit chunk 0 ----
#pragma unroll
    for (int ci = 0; ci < CI_CHUNK; ++ci) {
        const float* src = in_b + (size_t)ci * HW;
        rin[ci][0] = (soff[0] >= 0) ? src[soff[0]] : 0.f;
        rin[ci][1] = (soff[1] >= 0) ? src[soff[1]] : 0.f;
    }
#pragma unroll
    for (int s = 0; s < 9; ++s) rwt[s] = wgt[wgoff[s]];
#pragma unroll
    for (int ci = 0; ci < CI_CHUNK; ++ci) {
        s_in[0][ci * CH + tid] = rin[ci][0];
        if (tid < CELLS - 256) s_in[0][ci * CH + tid + 256] = rin[ci][1];
    }
#pragma unroll
    for (int s = 0; s < 9; ++s) s_w[0][lwoff[s]] = (double)rwt[s];
    __syncthreads();

#pragma unroll 2
    for (int c = 0; c < NCHUNK; ++c) {
        const int buf = c & 1;
        // ---- issue next chunk's global loads (land under the mfmas) ----
        if (c + 1 < NCHUNK) {
            const int c0n = (c + 1) * CI_CHUNK;
#pragma unroll
            for (int ci = 0; ci < CI_CHUNK; ++ci) {
                const float* src = in_b + (size_t)(c0n + ci) * HW;
                rin[ci][0] = (soff[0] >= 0) ? src[soff[0]] : 0.f;
                rin[ci][1] = (soff[1] >= 0) ? src[soff[1]] : 0.f;
            }
#pragma unroll
            for (int s = 0; s < 9; ++s) rwt[s] = wgt[wgoff[s] + c0n * 9];
        }
        // ---- compute: 9 taps x 2 ci4-groups x 8 D-tiles = 144 mfma ----
        {
            const float*  ti = &s_in[buf][0];
            const double* tw = &s_w[buf][0];
#pragma unroll
            for (int tap = 0; tap < 9; ++tap) {
                const int ky = tap / 3, kx = tap % 3;
#pragma unroll
                for (int g = 0; g < 2; ++g) {
                    const int ka = g * 4 * CH + ky * TW + kx;
                    const int kb = g * 4 * WST + tap * 32;
                    const double b0 = tw[bbase0 + kb];
                    const double b1 = tw[bbase1 + kb];
                    const double a0 = (double)ti[abase[0] + ka];
                    const double a1 = (double)ti[abase[1] + ka];
                    const double a2 = (double)ti[abase[2] + ka];
                    const double a3 = (double)ti[abase[3] + ka];
                    acc[0][0] = __builtin_amdgcn_mfma_f64_16x16x4f64(a0, b0, acc[0][0], 0, 0, 0);
                    acc[0][1] = __builtin_amdgcn_mfma_f64_16x16x4f64(a0, b1, acc[0][1], 0, 0, 0);
                    acc[1][0] = __builtin_amdgcn_mfma_f64_16x16x4f64(a1, b0, acc[1][0], 0, 0, 0);
                    acc[1][1] = __builtin_amdgcn_mfma_f64_16x16x4f64(a1, b1, acc[1][1], 0, 0, 0);
                    acc[2][0] = __builtin_amdgcn_mfma_f64_16x16x4f64(a2, b0, acc[2][0], 0, 0, 0);
                    acc[2][1] = __builtin_amdgcn_mfma_f64_16x16x4f64(a2, b1, acc[2][1], 0, 0, 0);
                    acc[3][0] = __builtin_amdgcn_mfma_f64_16x16x4f64(a3, b0, acc[3][0], 0, 0, 0);
                    acc[3][1] = __builtin_amdgcn_mfma_f64_16x16x4f64(a3, b1, acc[3][1], 0, 0, 0);
                }
            }
        }
        // ---- commit prefetched regs to the other buffer, one barrier ----
        if (c + 1 < NCHUNK) {
#pragma unroll
            for (int ci = 0; ci < CI_CHUNK; ++ci) {
                s_in[buf ^ 1][ci * CH + tid] = rin[ci][0];
                if (tid < CELLS - 256) s_in[buf ^ 1][ci * CH + tid + 256] = rin[ci][1];
            }
#pragma unroll
            for (int s = 0; s < 9; ++s) s_w[buf ^ 1][lwoff[s]] = (double)rwt[s];
            __syncthreads();
        }
    }

    // ---- epilogue: bias (f64) -> relu (f32) -> 2x2 maxpool -> store.
    // Reg r of acc[m][n] holds pre-pool x = x0 + xh*16 + 4r + l4, y = y0+2wv+dy.
    // Vertical pool intra-thread (m pairs); horizontal partner x^1 = lane^16.
    const int yp = (y0 >> 1) + wv;
#pragma unroll
    for (int n = 0; n < 2; ++n) {
        const int co = cob * 32 + n * 16 + l15;
        const double bd = (double)bias[co];
        float* orow = out + (((size_t)b * Cout + co) * Hp + yp) * Wp;
#pragma unroll
        for (int xh = 0; xh < 2; ++xh) {
#pragma unroll
            for (int r = 0; r < 4; ++r) {
                const float e0 = fmaxf((float)(acc[xh][n][r]     + bd), 0.f);
                const float e1 = fmaxf((float)(acc[2 + xh][n][r] + bd), 0.f);
                float v = fmaxf(e0, e1);                 // vertical pool
                const float p = __shfl_xor(v, 16, 64);   // horizontal partner
                v = fmaxf(v, p);
                if ((l4 & 1) == 0) {
                    const int xp = (x0 >> 1) + xh * 8 + 2 * r + (l4 >> 1);
                    orow[xp] = v;
                }
            }
        }
    }
}

// ---------------------------------------------------------------------------
// Head 1x1 conv (256->5, f64) + decode (f64) -> boxes/scores. 32 blocks.
// ---------------------------------------------------------------------------
__launch_bounds__(256)
__global__ void head_decode_k(const float* __restrict__ x4,
                              const float* __restrict__ wh,
                              const float* __restrict__ bh,
                              float* __restrict__ boxes,
                              float* __restrict__ scores) {
    __shared__ float s_wh[5 * 256];
    const int tid = threadIdx.x;
#pragma unroll
    for (int i = 0; i < 5; ++i) s_wh[i * 256 + tid] = wh[i * 256 + tid];
    __syncthreads();

    const int idx  = blockIdx.x * 256 + tid;  // 0..8191
    const int b    = idx >> 10;
    const int cell = idx & 1023;
    const int gy = cell >> 5, gx = cell & 31;

    double a0 = (double)bh[0], a1 = (double)bh[1], a2 = (double)bh[2],
           a3 = (double)bh[3], a4 = (double)bh[4];
    const float* xp = x4 + b * 262144 + cell;
    for (int ci = 0; ci < 256; ++ci) {
        const double v = (double)xp[ci << 10];
        a0 = fma(v, (double)s_wh[0 * 256 + ci], a0);
        a1 = fma(v, (double)s_wh[1 * 256 + ci], a1);
        a2 = fma(v, (double)s_wh[2 * 256 + ci], a2);
        a3 = fma(v, (double)s_wh[3 * 256 + ci], a3);
        a4 = fma(v, (double)s_wh[4 * 256 + ci], a4);
    }
    const double obj = 1.0 / (1.0 + exp(-a0));
    const double txs = 1.0 / (1.0 + exp(-a1));
    const double tys = 1.0 / (1.0 + exp(-a2));
    const double bw  = exp(a3) * 16.0;
    const double bhh = exp(a4) * 16.0;
    const double cx  = gx * 16.0 + txs * 16.0;
    const double cy  = gy * 16.0 + tys * 16.0;
    float* bp = boxes + idx * 4;
    bp[0] = (float)fmin(fmax(cx - bw * 0.5, 0.0), 511.0);
    bp[1] = (float)fmin(fmax(cy - bhh * 0.5, 0.0), 511.0);
    bp[2] = (float)fmin(fmax(cx + bw * 0.5, 0.0), 511.0);
    bp[3] = (float)fmin(fmax(cy + bhh * 0.5, 0.0), 511.0);
    scores[idx] = (float)obj;
}

// ---------------------------------------------------------------------------
// Per-batch top-200 (bitonic, lax.top_k tie semantics) + greedy NMS + output.
// ---------------------------------------------------------------------------
__launch_bounds__(256)
__global__ void topk_nms_k(const float* __restrict__ boxes,
                           const float* __restrict__ scores,
                           float* __restrict__ out5,
                           float* __restrict__ keep_out) {
    const int b = blockIdx.x, tid = threadIdx.x;
    __shared__ unsigned long long key[1024];
    __shared__ float bx1[TOPK_N], by1[TOPK_N], bx2[TOPK_N], by2[TOPK_N];
    __shared__ float sv[TOPK_N], ar[TOPK_N];
    __shared__ int   kp[TOPK_N];

    for (int i = tid; i < 1024; i += 256) {
        float s = scores[b * 1024 + i];
        float m = (s >= 0.01f) ? s : -1.0f;
        unsigned u = __float_as_uint(m);
        u = (u & 0x80000000u) ? ~u : (u | 0x80000000u);
        key[i] = ((unsigned long long)u << 32) | (unsigned)(1023 - i);
    }
    __syncthreads();

    for (int k = 2; k <= 1024; k <<= 1) {
        for (int j = k >> 1; j > 0; j >>= 1) {
            for (int i = tid; i < 1024; i += 256) {
                int l = i ^ j;
                if (l > i) {
                    unsigned long long a = key[i], c = key[l];
                    bool desc = ((i & k) == 0);
                    bool sw = desc ? (a < c) : (a > c);
                    if (sw) { key[i] = c; key[l] = a; }
                }
            }
            __syncthreads();
        }
    }

    for (int i = tid; i < TOPK_N; i += 256) {
        unsigned long long kk = key[i];
        unsigned u = (unsigned)(kk >> 32);
        unsigned bits = (u & 0x80000000u) ? (u & 0x7FFFFFFFu) : ~u;
        float s = __uint_as_float(bits);
        int src = 1023 - (int)(kk & 0xFFFFFFFFu);
        const float4 bb = *(const float4*)(boxes + (b * 1024 + src) * 4);
        bx1[i] = bb.x; by1[i] = bb.y; bx2[i] = bb.z; by2[i] = bb.w;
        sv[i] = s;
        ar[i] = (bb.z - bb.x) * (bb.w - bb.y);
        kp[i] = (s >= 0.01f) ? 1 : 0;
    }
    __syncthreads();

    for (int i = 0; i < TOPK_N; ++i) {
        if (kp[i]) {
            const float X1 = bx1[i], Y1 = by1[i], X2 = bx2[i], Y2 = by2[i], A = ar[i];
            for (int j = tid; j < TOPK_N; j += 256) {
                if (j > i && kp[j]) {
                    float xx1 = fmaxf(X1, bx1[j]);
                    float yy1 = fmaxf(Y1, by1[j]);
                    float xx2 = fminf(X2, bx2[j]);
                    float yy2 = fminf(Y2, by2[j]);
                    float inter = fmaxf(xx2 - xx1, 0.f) * fmaxf(yy2 - yy1, 0.f);
                    float uni = A + ar[j] - inter;
                    float iou = inter / fmaxf(uni, 1e-6f);
                    if (iou > 0.5f) kp[j] = 0;
                }
            }
        }
        __syncthreads();
    }

    for (int i = tid; i < TOPK_N; i += 256) {
        float kf = kp[i] ? 1.f : 0.f;
        float s  = sv[i];
        float sc = (s >= 0.01f) ? s : 0.f;
        float* op = out5 + (b * TOPK_N + i) * 5;
        op[0] = bx1[i] * kf;
        op[1] = by1[i] * kf;
        op[2] = bx2[i] * kf;
        op[3] = by2[i] * kf;
        op[4] = sc * kf;
        keep_out[b * TOPK_N + i] = kf;
    }
}

extern "C" void kernel_launch(void* const* d_in, const int* in_sizes, int n_in,
                              void* d_out, int out_size, void* d_ws, size_t ws_size,
                              hipStream_t stream) {
    const float* images = (const float*)d_in[0];
    const float* w1 = (const float*)d_in[1];
    const float* b1 = (const float*)d_in[2];
    const float* w2 = (const float*)d_in[3];
    const float* b2 = (const float*)d_in[4];
    const float* w3 = (const float*)d_in[5];
    const float* b3 = (const float*)d_in[6];
    const float* w4 = (const float*)d_in[7];
    const float* b4 = (const float*)d_in[8];
    const float* wh = (const float*)d_in[9];
    const float* bh = (const float*)d_in[10];
    float* out = (float*)d_out;

    float* A    = (float*)d_ws;          // x1 [8,32,256,256] -> x3 [8,128,64,64]
    float* Bbuf = A + 16777216;          // x2 [8,64,128,128] -> x4 [8,256,32,32]
    float* boxes  = A + 8388608;         // dead x1 space: 32768 floats
    float* scores = A + 8388608 + 32768; //  8192 floats

    // L1: 3->32, 512x512 -> 256x256. VALU-f64 template (CIN=3 not mfma-shaped).
    conv_relu_pool_pipe<3, 3, 8><<<dim3(16, 16, 8 * 4), 256, 0, stream>>>(
        images, w1, b1, A, 512, 512, 32);
    // L2: 32->64, 256x256 in. MFMA-f64: grid (Wpre/32, Hpre/8, B*Cout/32).
    conv_mfma_f64<32><<<dim3(8, 32, 8 * 2), 256, 0, stream>>>(
        A, w2, b2, Bbuf, 256, 256, 64);
    // L3: 64->128, 128x128 in.
    conv_mfma_f64<64><<<dim3(4, 16, 8 * 4), 256, 0, stream>>>(
        Bbuf, w3, b3, A, 128, 128, 128);
    // L4: 128->256, 64x64 in.
    conv_mfma_f64<128><<<dim3(2, 8, 8 * 8), 256, 0, stream>>>(
        A, w4, b4, Bbuf, 64, 64, 256);
    // Head + decode: 32 blocks, coalesced
    head_decode_k<<<32, 256, 0, stream>>>(Bbuf, wh, bh, boxes, scores);
    // Top-k + NMS + output
    topk_nms_k<<<8, 256, 0, stream>>>(boxes, scores, out, out + 8 * TOPK_N * 5);
}

// Round 8
// 1213.054 us; speedup vs baseline: 1.1205x; 1.0173x over previous
//
#include <hip/hip_runtime.h>
#include <math.h>

// f32 I/O, f64 accumulation everywhere (bit-exact vs np-f64 ref at f32
// materialization points — absmax 0.0 R4-R17). Workspace 96 MiB.
//
// R18 = R13 (best: 1212 µs) + EXPLICIT g-iter software pipeline.
// Falsified so far: load latency at chunk level (R16), inter-block phase
// lock (R17), 3-wave occupancy (R14/R15 spill/regress). The surviving
// theory: R12 (single-wave) showed per-wave MFMA duty of only 57% — each
// g-iter has ~390 cy of serial ds_read+cvt+wait gap the compiler fails to
// hoist past the previous 512-cy mfma cluster (no reg headroom at 188).
// R18 prefetches g-iter kk+1's operands (4 A f32, 2 B f64 -> 12 VGPRs)
// into named regs BEFORE kk's 8 mfmas, in source order; schedulers hoist
// loads but do not sink them, so the pipeline sticks. mfma order per
// accumulator unchanged -> absmax 0.0 preserved. R17's s_sleep dropped
// (neutral on time, cost 46 MB of L2 locality).

constexpr int TOPK_N = 200;

typedef double f64x4 __attribute__((ext_vector_type(4)));

// ---------------------------------------------------------------------------
// L1 only (CIN=3): R10 VALU-f64 tiled fused conv+bias+relu+pool, pipelined.
// Block = 256 threads = 16x16 pooled outputs (32x32 pre-pool), CO_BLK=8.
// ---------------------------------------------------------------------------
template <int CIN, int CI_BLK, int CO_BLK>
__launch_bounds__(256)
__global__ void conv_relu_pool_pipe(const float* __restrict__ in,
                                    const float* __restrict__ wgt,
                                    const float* __restrict__ bias,
                                    float* __restrict__ out,
                                    int Hin, int Win, int Cout) {
    constexpr int SPATIAL = 34 * 34;               // 1156
    constexpr int SSLOT = (SPATIAL + 255) / 256;   // 5
    constexpr int NW = CI_BLK * 9 * CO_BLK;        // weights per chunk
    constexpr int NCHUNK = CIN / CI_BLK;
    const int Hp = Hin >> 1, Wp = Win >> 1;
    const int coChunks = Cout / CO_BLK;
    const int b  = blockIdx.z / coChunks;
    const int cz = blockIdx.z % coChunks;
    const int tid = threadIdx.x;
    const int tx = tid & 15, ty = tid >> 4;
    const int px = (blockIdx.x << 4) + tx;
    const int py = (blockIdx.y << 4) + ty;
    const int iy0 = (blockIdx.y << 5) - 1;
    const int ix0 = (blockIdx.x << 5) - 1;

    __shared__ float  s_in[2][CI_BLK * SPATIAL];
    __shared__ double s_w[2][NW];

    int soff[SSLOT];
#pragma unroll
    for (int s = 0; s < SSLOT; ++s) {
        const int cell = tid + s * 256;
        int g = -1;
        if (cell < SPATIAL) {
            const int ly = cell / 34, lx = cell - ly * 34;
            const int iy = iy0 + ly, ix = ix0 + lx;
            if ((unsigned)iy < (unsigned)Hin && (unsigned)ix < (unsigned)Win)
                g = iy * Win + ix;
        }
        soff[s] = g;
    }
    int wg = -1;
    if (tid < NW) {
        const int co   = tid & (CO_BLK - 1);
        const int rest = tid / CO_BLK;
        const int k    = rest % 9;
        const int ci   = rest / 9;
        wg = ((cz * CO_BLK + co) * CIN + ci) * 9 + k;
    }
    const size_t HW = (size_t)Hin * Win;
    const float* in_b = in + (size_t)b * CIN * HW;

    double acc[CO_BLK][4];
#pragma unroll
    for (int co = 0; co < CO_BLK; ++co)
#pragma unroll
        for (int p = 0; p < 4; ++p) acc[co][p] = 0.0;

    float rin[CI_BLK][SSLOT];
    float rw = 0.f;

#pragma unroll
    for (int ci = 0; ci < CI_BLK; ++ci) {
        const float* src = in_b + ci * HW;
#pragma unroll
        for (int s = 0; s < SSLOT; ++s) {
            const int cell = tid + s * 256;
            float v = 0.f;
            if (cell < SPATIAL) { const int g = soff[s]; if (g >= 0) v = src[g]; }
            rin[ci][s] = v;
        }
    }
    if (tid < NW) rw = wgt[wg];
#pragma unroll
    for (int ci = 0; ci < CI_BLK; ++ci)
#pragma unroll
        for (int s = 0; s < SSLOT; ++s) {
            const int cell = tid + s * 256;
            if (cell < SPATIAL) s_in[0][ci * SPATIAL + cell] = rin[ci][s];
        }
    if (tid < NW) s_w[0][tid] = (double)rw;
    __syncthreads();

    for (int c = 0; c < NCHUNK; ++c) {
        const int buf = c & 1;
        if (c + 1 < NCHUNK) {
            const int c0n = (c + 1) * CI_BLK;
#pragma unroll
            for (int ci = 0; ci < CI_BLK; ++ci) {
                const float* src = in_b + (c0n + ci) * HW;
#pragma unroll
                for (int s = 0; s < SSLOT; ++s) {
                    const int cell = tid + s * 256;
                    float v = 0.f;
                    if (cell < SPATIAL) { const int g = soff[s]; if (g >= 0) v = src[g]; }
                    rin[ci][s] = v;
                }
            }
            if (tid < NW) rw = wgt[wg + c0n * 9];
        }
#pragma unroll 1
        for (int ci = 0; ci < CI_BLK; ++ci) {
            const float* tile = &s_in[buf][ci * SPATIAL];
            double win[4][4];
#pragma unroll
            for (int iy = 0; iy < 4; ++iy) {
                float2 r0 = *(const float2*)&tile[(2 * ty + iy) * 34 + 2 * tx];
                float2 r1 = *(const float2*)&tile[(2 * ty + iy) * 34 + 2 * tx + 2];
                win[iy][0] = (double)r0.x; win[iy][1] = (double)r0.y;
                win[iy][2] = (double)r1.x; win[iy][3] = (double)r1.y;
            }
#pragma unroll
            for (int k = 0; k < 9; ++k) {
                const int ky = k / 3, kx = k % 3;
                const double* wp = &s_w[buf][(ci * 9 + k) * CO_BLK];
                double w[CO_BLK];
#pragma unroll
                for (int co = 0; co < CO_BLK; ++co) w[co] = wp[co];
#pragma unroll
                for (int p = 0; p < 4; ++p) {
                    const double v = win[(p >> 1) + ky][(p & 1) + kx];
#pragma unroll
                    for (int co = 0; co < CO_BLK; ++co)
                        acc[co][p] = fma(v, w[co], acc[co][p]);
                }
            }
        }
        if (c + 1 < NCHUNK) {
#pragma unroll
            for (int ci = 0; ci < CI_BLK; ++ci)
#pragma unroll
                for (int s = 0; s < SSLOT; ++s) {
                    const int cell = tid + s * 256;
                    if (cell < SPATIAL) s_in[buf ^ 1][ci * SPATIAL + cell] = rin[ci][s];
                }
            if (tid < NW) s_w[buf ^ 1][tid] = (double)rw;
            __syncthreads();
        }
    }

#pragma unroll
    for (int co = 0; co < CO_BLK; ++co) {
        const double bd = (double)bias[cz * CO_BLK + co];
        const float e0 = fmaxf((float)(acc[co][0] + bd), 0.f);
        const float e1 = fmaxf((float)(acc[co][1] + bd), 0.f);
        const float e2 = fmaxf((float)(acc[co][2] + bd), 0.f);
        const float e3 = fmaxf((float)(acc[co][3] + bd), 0.f);
        out[((size_t)(b * Cout + cz * CO_BLK + co) * Hp + py) * Wp + px] =
            fmaxf(fmaxf(e0, e1), fmaxf(e2, e3));
    }
}

// ---------------------------------------------------------------------------
// L2-L4: implicit-GEMM conv via v_mfma_f64_16x16x4 (R18 = R13 + g-pipeline).
// Block = 256 thr = 4 waves; tile = 32x8 pre-pool spatial x 32 cout.
// Layouts (CK xdlops, f64 group_size=1):
//   A lane l -> A[i=l&15][k=l>>4];  B lane l -> B[k=l>>4][j=l&15];
//   D lane l reg r -> D[row = 4*r + (l>>4)][col = l&15]   (REGISTER-major)
// Pooling: vertical intra-thread (m pairs), horizontal via __shfl_xor(16).
// LDS: in f32 2x8x360 + w f64 2x8x296 = 60928 B (2 blocks/CU).
// Compute loop: kk = tap*2+g flattened; operands of kk+1 loaded into named
// regs BEFORE kk's 8 mfmas (depth-1 software pipeline; ds latency hides
// under the 512-cy mfma cluster). mfma order per acc identical to R13.
// ---------------------------------------------------------------------------
template <int CIN>
__launch_bounds__(256, 2)
__global__ void conv_mfma_f64(const float* __restrict__ in,
                              const float* __restrict__ wgt,
                              const float* __restrict__ bias,
                              float* __restrict__ out,
                              int Hin, int Win, int Cout) {
    constexpr int TW = 34;               // halo tile width  (32 + 2)
    constexpr int CELLS = 34 * 10;       // halo tile cells  (8 + 2 rows)
    constexpr int CH = 360;              // padded per-ci input stride (f32)
    constexpr int CI_CHUNK = 8;
    constexpr int NCHUNK = CIN / CI_CHUNK;
    constexpr int WST = 296;             // per-ci weight stride (f64 elems)

    const int Hp = Hin >> 1, Wp = Win >> 1;
    const int coChunks = Cout >> 5;
    const int b   = blockIdx.z / coChunks;
    const int cob = blockIdx.z % coChunks;
    const int tid = threadIdx.x;
    const int wv  = tid >> 6;
    const int l15 = tid & 15;
    const int l4  = (tid >> 4) & 3;
    const int x0 = blockIdx.x << 5;      // pre-pool tile origin x (32 wide)
    const int y0 = blockIdx.y << 3;      // pre-pool tile origin y (8 tall)

    __shared__ float  s_in[2][CI_CHUNK * CH];
    __shared__ double s_w[2][CI_CHUNK * WST];

    // ---- chunk-invariant staging geometry ----
    int soff[2];
#pragma unroll
    for (int s = 0; s < 2; ++s) {
        const int cell = tid + s * 256;
        int g = -1;
        if (cell < CELLS) {
            const int ly = cell / TW, lx = cell - ly * TW;
            const int iy = y0 - 1 + ly, ix = x0 - 1 + lx;
            if ((unsigned)iy < (unsigned)Hin && (unsigned)ix < (unsigned)Win)
                g = iy * Win + ix;
        }
        soff[s] = g;
    }
    int wgoff[9], lwoff[9];              // 2304 = 9*256 weight slots exactly
#pragma unroll
    for (int s = 0; s < 9; ++s) {
        const int idx  = s * 256 + tid;
        const int co_l = idx & 31;
        const int r    = idx >> 5;       // 0..71
        const int tap  = r % 9;
        const int ci_l = r / 9;          // 0..7
        wgoff[s] = ((cob * 32 + co_l) * CIN + ci_l) * 9 + tap;
        lwoff[s] = ci_l * WST + tap * 32 + co_l;
    }
    const size_t HW = (size_t)Hin * Win;
    const float* in_b = in + (size_t)b * CIN * HW;

    // ---- per-wave mfma read bases (element indices) ----
    int abase[4];
#pragma unroll
    for (int m = 0; m < 4; ++m) {
        const int dy = m >> 1, xh = m & 1;
        abase[m] = l4 * CH + (2 * wv + dy) * TW + xh * 16 + l15;
    }
    const int bbase0 = l4 * WST + l15;
    const int bbase1 = l4 * WST + 16 + l15;

    f64x4 acc[4][2];
#pragma unroll
    for (int m = 0; m < 4; ++m)
#pragma unroll
        for (int n = 0; n < 2; ++n)
#pragma unroll
            for (int j = 0; j < 4; ++j) acc[m][n][j] = 0.0;

    float rin[CI_CHUNK][2];
    float rwt[9];

    // ---- prologue: fetch + commit chunk 0 ----
#pragma unroll
    for (int ci = 0; ci < CI_CHUNK; ++ci) {
        const float* src = in_b + (size_t)ci * HW;
        rin[ci][0] = (soff[0] >= 0) ? src[soff[0]] : 0.f;
        rin[ci][1] = (soff[1] >= 0) ? src[soff[1]] : 0.f;
    }
#pragma unroll
    for (int s = 0; s < 9; ++s) rwt[s] = wgt[wgoff[s]];
#pragma unroll
    for (int ci = 0; ci < CI_CHUNK; ++ci) {
        s_in[0][ci * CH + tid] = rin[ci][0];
        if (tid < CELLS - 256) s_in[0][ci * CH + tid + 256] = rin[ci][1];
    }
#pragma unroll
    for (int s = 0; s < 9; ++s) s_w[0][lwoff[s]] = (double)rwt[s];
    __syncthreads();

    // kk = tap*2 + g; ka/kb offsets are compile-time in the unrolled loop.
#define R18_KA(kk) ((((kk)&1) * 4 * CH) + ((((kk)>>1) / 3) * TW) + (((kk)>>1) % 3))
#define R18_KB(kk) ((((kk)&1) * 4 * WST) + (((kk)>>1) * 32))

#pragma unroll 2
    for (int c = 0; c < NCHUNK; ++c) {
        const int buf = c & 1;
        // ---- issue next chunk's global loads (land under the mfmas) ----
        if (c + 1 < NCHUNK) {
            const int c0n = (c + 1) * CI_CHUNK;
#pragma unroll
            for (int ci = 0; ci < CI_CHUNK; ++ci) {
                const float* src = in_b + (size_t)(c0n + ci) * HW;
                rin[ci][0] = (soff[0] >= 0) ? src[soff[0]] : 0.f;
                rin[ci][1] = (soff[1] >= 0) ? src[soff[1]] : 0.f;
            }
#pragma unroll
            for (int s = 0; s < 9; ++s) rwt[s] = wgt[wgoff[s] + c0n * 9];
        }
        // ---- compute: 18 kk-iters x 8 D-tiles = 144 mfma, depth-1 pipeline ----
        {
            const float*  ti = &s_in[buf][0];
            const double* tw = &s_w[buf][0];
            double A0, A1, A2, A3, B0, B1;
            B0 = tw[bbase0 + R18_KB(0)];
            B1 = tw[bbase1 + R18_KB(0)];
            A0 = (double)ti[abase[0] + R18_KA(0)];
            A1 = (double)ti[abase[1] + R18_KA(0)];
            A2 = (double)ti[abase[2] + R18_KA(0)];
            A3 = (double)ti[abase[3] + R18_KA(0)];
#pragma unroll
            for (int kk = 0; kk < 18; ++kk) {
                double nA0, nA1, nA2, nA3, nB0, nB1;
                if (kk + 1 < 18) {
                    nB0 = tw[bbase0 + R18_KB(kk + 1)];
                    nB1 = tw[bbase1 + R18_KB(kk + 1)];
                    nA0 = (double)ti[abase[0] + R18_KA(kk + 1)];
                    nA1 = (double)ti[abase[1] + R18_KA(kk + 1)];
                    nA2 = (double)ti[abase[2] + R18_KA(kk + 1)];
                    nA3 = (double)ti[abase[3] + R18_KA(kk + 1)];
                }
                acc[0][0] = __builtin_amdgcn_mfma_f64_16x16x4f64(A0, B0, acc[0][0], 0, 0, 0);
                acc[0][1] = __builtin_amdgcn_mfma_f64_16x16x4f64(A0, B1, acc[0][1], 0, 0, 0);
                acc[1][0] = __builtin_amdgcn_mfma_f64_16x16x4f64(A1, B0, acc[1][0], 0, 0, 0);
                acc[1][1] = __builtin_amdgcn_mfma_f64_16x16x4f64(A1, B1, acc[1][1], 0, 0, 0);
                acc[2][0] = __builtin_amdgcn_mfma_f64_16x16x4f64(A2, B0, acc[2][0], 0, 0, 0);
                acc[2][1] = __builtin_amdgcn_mfma_f64_16x16x4f64(A2, B1, acc[2][1], 0, 0, 0);
                acc[3][0] = __builtin_amdgcn_mfma_f64_16x16x4f64(A3, B0, acc[3][0], 0, 0, 0);
                acc[3][1] = __builtin_amdgcn_mfma_f64_16x16x4f64(A3, B1, acc[3][1], 0, 0, 0);
                if (kk + 1 < 18) {
                    A0 = nA0; A1 = nA1; A2 = nA2; A3 = nA3;
                    B0 = nB0; B1 = nB1;
                }
            }
        }
        // ---- commit prefetched regs to the other buffer, one barrier ----
        if (c + 1 < NCHUNK) {
#pragma unroll
            for (int ci = 0; ci < CI_CHUNK; ++ci) {
                s_in[buf ^ 1][ci * CH + tid] = rin[ci][0];
                if (tid < CELLS - 256) s_in[buf ^ 1][ci * CH + tid + 256] = rin[ci][1];
            }
#pragma unroll
            for (int s = 0; s < 9; ++s) s_w[buf ^ 1][lwoff[s]] = (double)rwt[s];
            __syncthreads();
        }
    }
#undef R18_KA
#undef R18_KB

    // ---- epilogue: bias (f64) -> relu (f32) -> 2x2 maxpool -> store.
    // Reg r of acc[m][n] holds pre-pool x = x0 + xh*16 + 4r + l4, y = y0+2wv+dy.
    // Vertical pool intra-thread (m pairs); horizontal partner x^1 = lane^16.
    const int yp = (y0 >> 1) + wv;
#pragma unroll
    for (int n = 0; n < 2; ++n) {
        const int co = cob * 32 + n * 16 + l15;
        const double bd = (double)bias[co];
        float* orow = out + (((size_t)b * Cout + co) * Hp + yp) * Wp;
#pragma unroll
        for (int xh = 0; xh < 2; ++xh) {
#pragma unroll
            for (int r = 0; r < 4; ++r) {
                const float e0 = fmaxf((float)(acc[xh][n][r]     + bd), 0.f);
                const float e1 = fmaxf((float)(acc[2 + xh][n][r] + bd), 0.f);
                float v = fmaxf(e0, e1);                 // vertical pool
                const float p = __shfl_xor(v, 16, 64);   // horizontal partner
                v = fmaxf(v, p);
                if ((l4 & 1) == 0) {
                    const int xp = (x0 >> 1) + xh * 8 + 2 * r + (l4 >> 1);
                    orow[xp] = v;
                }
            }
        }
    }
}

// ---------------------------------------------------------------------------
// Head 1x1 conv (256->5, f64) + decode (f64) -> boxes/scores. 32 blocks.
// ---------------------------------------------------------------------------
__launch_bounds__(256)
__global__ void head_decode_k(const float* __restrict__ x4,
                              const float* __restrict__ wh,
                              const float* __restrict__ bh,
                              float* __restrict__ boxes,
                              float* __restrict__ scores) {
    __shared__ float s_wh[5 * 256];
    const int tid = threadIdx.x;
#pragma unroll
    for (int i = 0; i < 5; ++i) s_wh[i * 256 + tid] = wh[i * 256 + tid];
    __syncthreads();

    const int idx  = blockIdx.x * 256 + tid;  // 0..8191
    const int b    = idx >> 10;
    const int cell = idx & 1023;
    const int gy = cell >> 5, gx = cell & 31;

    double a0 = (double)bh[0], a1 = (double)bh[1], a2 = (double)bh[2],
           a3 = (double)bh[3], a4 = (double)bh[4];
    const float* xp = x4 + b * 262144 + cell;
    for (int ci = 0; ci < 256; ++ci) {
        const double v = (double)xp[ci << 10];
        a0 = fma(v, (double)s_wh[0 * 256 + ci], a0);
        a1 = fma(v, (double)s_wh[1 * 256 + ci], a1);
        a2 = fma(v, (double)s_wh[2 * 256 + ci], a2);
        a3 = fma(v, (double)s_wh[3 * 256 + ci], a3);
        a4 = fma(v, (double)s_wh[4 * 256 + ci], a4);
    }
    const double obj = 1.0 / (1.0 + exp(-a0));
    const double txs = 1.0 / (1.0 + exp(-a1));
    const double tys = 1.0 / (1.0 + exp(-a2));
    const double bw  = exp(a3) * 16.0;
    const double bhh = exp(a4) * 16.0;
    const double cx  = gx * 16.0 + txs * 16.0;
    const double cy  = gy * 16.0 + tys * 16.0;
    float* bp = boxes + idx * 4;
    bp[0] = (float)fmin(fmax(cx - bw * 0.5, 0.0), 511.0);
    bp[1] = (float)fmin(fmax(cy - bhh * 0.5, 0.0), 511.0);
    bp[2] = (float)fmin(fmax(cx + bw * 0.5, 0.0), 511.0);
    bp[3] = (float)fmin(fmax(cy + bhh * 0.5, 0.0), 511.0);
    scores[idx] = (float)obj;
}

// ---------------------------------------------------------------------------
// Per-batch top-200 (bitonic, lax.top_k tie semantics) + greedy NMS + output.
// ---------------------------------------------------------------------------
__launch_bounds__(256)
__global__ void topk_nms_k(const float* __restrict__ boxes,
                           const float* __restrict__ scores,
                           float* __restrict__ out5,
                           float* __restrict__ keep_out) {
    const int b = blockIdx.x, tid = threadIdx.x;
    __shared__ unsigned long long key[1024];
    __shared__ float bx1[TOPK_N], by1[TOPK_N], bx2[TOPK_N], by2[TOPK_N];
    __shared__ float sv[TOPK_N], ar[TOPK_N];
    __shared__ int   kp[TOPK_N];

    for (int i = tid; i < 1024; i += 256) {
        float s = scores[b * 1024 + i];
        float m = (s >= 0.01f) ? s : -1.0f;
        unsigned u = __float_as_uint(m);
        u = (u & 0x80000000u) ? ~u : (u | 0x80000000u);
        key[i] = ((unsigned long long)u << 32) | (unsigned)(1023 - i);
    }
    __syncthreads();

    for (int k = 2; k <= 1024; k <<= 1) {
        for (int j = k >> 1; j > 0; j >>= 1) {
            for (int i = tid; i < 1024; i += 256) {
                int l = i ^ j;
                if (l > i) {
                    unsigned long long a = key[i], c = key[l];
                    bool desc = ((i & k) == 0);
                    bool sw = desc ? (a < c) : (a > c);
                    if (sw) { key[i] = c; key[l] = a; }
                }
            }
            __syncthreads();
        }
    }

    for (int i = tid; i < TOPK_N; i += 256) {
        unsigned long long kk = key[i];
        unsigned u = (unsigned)(kk >> 32);
        unsigned bits = (u & 0x80000000u) ? (u & 0x7FFFFFFFu) : ~u;
        float s = __uint_as_float(bits);
        int src = 1023 - (int)(kk & 0xFFFFFFFFu);
        const float4 bb = *(const float4*)(boxes + (b * 1024 + src) * 4);
        bx1[i] = bb.x; by1[i] = bb.y; bx2[i] = bb.z; by2[i] = bb.w;
        sv[i] = s;
        ar[i] = (bb.z - bb.x) * (bb.w - bb.y);
        kp[i] = (s >= 0.01f) ? 1 : 0;
    }
    __syncthreads();

    for (int i = 0; i < TOPK_N; ++i) {
        if (kp[i]) {
            const float X1 = bx1[i], Y1 = by1[i], X2 = bx2[i], Y2 = by2[i], A = ar[i];
            for (int j = tid; j < TOPK_N; j += 256) {
                if (j > i && kp[j]) {
                    float xx1 = fmaxf(X1, bx1[j]);
                    float yy1 = fmaxf(Y1, by1[j]);
                    float xx2 = fminf(X2, bx2[j]);
                    float yy2 = fminf(Y2, by2[j]);
                    float inter = fmaxf(xx2 - xx1, 0.f) * fmaxf(yy2 - yy1, 0.f);
                    float uni = A + ar[j] - inter;
                    float iou = inter / fmaxf(uni, 1e-6f);
                    if (iou > 0.5f) kp[j] = 0;
                }
            }
        }
        __syncthreads();
    }

    for (int i = tid; i < TOPK_N; i += 256) {
        float kf = kp[i] ? 1.f : 0.f;
        float s  = sv[i];
        float sc = (s >= 0.01f) ? s : 0.f;
        float* op = out5 + (b * TOPK_N + i) * 5;
        op[0] = bx1[i] * kf;
        op[1] = by1[i] * kf;
        op[2] = bx2[i] * kf;
        op[3] = by2[i] * kf;
        op[4] = sc * kf;
        keep_out[b * TOPK_N + i] = kf;
    }
}

extern "C" void kernel_launch(void* const* d_in, const int* in_sizes, int n_in,
                              void* d_out, int out_size, void* d_ws, size_t ws_size,
                              hipStream_t stream) {
    const float* images = (const float*)d_in[0];
    const float* w1 = (const float*)d_in[1];
    const float* b1 = (const float*)d_in[2];
    const float* w2 = (const float*)d_in[3];
    const float* b2 = (const float*)d_in[4];
    const float* w3 = (const float*)d_in[5];
    const float* b3 = (const float*)d_in[6];
    const float* w4 = (const float*)d_in[7];
    const float* b4 = (const float*)d_in[8];
    const float* wh = (const float*)d_in[9];
    const float* bh = (const float*)d_in[10];
    float* out = (float*)d_out;

    float* A    = (float*)d_ws;          // x1 [8,32,256,256] -> x3 [8,128,64,64]
    float* Bbuf = A + 16777216;          // x2 [8,64,128,128] -> x4 [8,256,32,32]
    float* boxes  = A + 8388608;         // dead x1 space: 32768 floats
    float* scores = A + 8388608 + 32768; //  8192 floats

    // L1: 3->32, 512x512 -> 256x256. VALU-f64 template (CIN=3 not mfma-shaped).
    conv_relu_pool_pipe<3, 3, 8><<<dim3(16, 16, 8 * 4), 256, 0, stream>>>(
        images, w1, b1, A, 512, 512, 32);
    // L2: 32->64, 256x256 in. MFMA-f64: grid (Wpre/32, Hpre/8, B*Cout/32).
    conv_mfma_f64<32><<<dim3(8, 32, 8 * 2), 256, 0, stream>>>(
        A, w2, b2, Bbuf, 256, 256, 64);
    // L3: 64->128, 128x128 in.
    conv_mfma_f64<64><<<dim3(4, 16, 8 * 4), 256, 0, stream>>>(
        Bbuf, w3, b3, A, 128, 128, 128);
    // L4: 128->256, 64x64 in.
    conv_mfma_f64<128><<<dim3(2, 8, 8 * 8), 256, 0, stream>>>(
        A, w4, b4, Bbuf, 64, 64, 256);
    // Head + decode: 32 blocks, coalesced
    head_decode_k<<<32, 256, 0, stream>>>(Bbuf, wh, bh, boxes, scores);
    // Top-k + NMS + output
    topk_nms_k<<<8, 256, 0, stream>>>(boxes, scores, out, out + 8 * TOPK_N * 5);
}